// Round 7
// baseline (238.853 us; speedup 1.0000x reference)
//
#include <hip/hip_runtime.h>
#include <hip/hip_bf16.h>
#include <cstddef>

// Problem constants
#define NN 16
#define CC 64
#define TT 300
#define VV 25
#define NHH 4
#define DKHH 16
#define BB (NN * VV)          // 400
#define EPS 1e-5f
#define LOG2E 1.4426950408889634f

// Workspace layout (u32 units)
#define WS_QK    0            // u32[400][64][300]  q|k bf16, paired along o (q pre-scaled 0.25*log2e)
#define WS_V     7680000      // u32[400][64][152]  v bf16, paired along t (t>=300 zero-filled)
#define WS_AH    11571200     // u32[400][64][152]  attnh bf16, paired along t
#define WS_REL   15462400     // u32[41][64][4] key_rel frags (slot = mtile+1, slot0 = zeros)
#define WS_AWF   15472896     // u32[4][2][64][4] attn_w B-frags (pre-scaled by bn scale)
#define WS_AOFF  15474944     // f32[64] fused attn_b+bn offset
#define WS_SCO   15475008     // f32[64] bn scale (for skip path)
#define WS_WFRAG 15475072     // u32[12][2][64][4] qkv_w B-frags (q pre-scaled 0.25*log2e)
#define WS_QB2   15481216     // f32[192] qkv_b (q pre-scaled)
#define WS_SCSH  15481408     // float2[1600] data_bn (sc, sh) per (c, v)

typedef __attribute__((ext_vector_type(8))) short short8;
typedef __attribute__((ext_vector_type(4))) float float4v;

union U8 { short8 v; unsigned int w[4]; };

// f32x2 -> packed bf16x2 (RNE). HW op if available, else manual.
__device__ __forceinline__ unsigned int pk2(float a, float b) {
#if __has_builtin(__builtin_amdgcn_cvt_pk_bf16_f32)
    typedef __attribute__((ext_vector_type(2))) __bf16 bf2;
    union { bf2 v; unsigned u; } c;
    c.v = __builtin_amdgcn_cvt_pk_bf16_f32(a, b);
    return c.u;
#else
    union { float f; unsigned u; } x, y;
    x.f = a; y.f = b;
    unsigned ua = x.u + 0x7FFFu + ((x.u >> 16) & 1u);
    unsigned ub = y.u + 0x7FFFu + ((y.u >> 16) & 1u);
    return (ua >> 16) | (ub & 0xFFFF0000u);
#endif
}

__device__ __forceinline__ float ex2(float x) {
#if __has_builtin(__builtin_amdgcn_exp2f)
    return __builtin_amdgcn_exp2f(x);
#else
    return exp2f(x);
#endif
}

__device__ __forceinline__ float rcpf_(float x) {
#if __has_builtin(__builtin_amdgcn_rcpf)
    return __builtin_amdgcn_rcpf(x);
#else
    return 1.f / x;
#endif
}

// ---------------------------------------------------------------------------
// k_pre: constant tables.
// ---------------------------------------------------------------------------
__global__ __launch_bounds__(256) void k_pre(
    const float* __restrict__ dbn_g, const float* __restrict__ dbn_b,
    const float* __restrict__ dbn_m, const float* __restrict__ dbn_v,
    const float* __restrict__ qkv_w, const float* __restrict__ qkv_b,
    const float* __restrict__ key_rel,
    const float* __restrict__ attn_w, const float* __restrict__ attn_b,
    const float* __restrict__ bn_g, const float* __restrict__ bn_b,
    const float* __restrict__ bn_m, const float* __restrict__ bn_v,
    unsigned* __restrict__ W)
{
    const int jid = blockIdx.x * 256 + threadIdx.x;
    if (jid < 2624) {                      // relfrag: 41 slots x 64 lanes
        const int k = jid >> 6, lane = jid & 63, col = lane & 15, quad = lane >> 4;
        const int mt = k - 1, m = mt * 16 + col;
        const bool ok = (quad < 2) && (mt >= 0) && (m < 2 * TT - 1);
        unsigned w[4];
        #pragma unroll
        for (int j2 = 0; j2 < 4; ++j2) {
            const int c = quad * 8 + 2 * j2;
            const float v0 = ok ? key_rel[m * 16 + c] : 0.f;
            const float v1 = ok ? key_rel[m * 16 + c + 1] : 0.f;
            w[j2] = pk2(v0, v1);
        }
        *(uint4*)&W[WS_REL + k * 256 + lane * 4] = make_uint4(w[0], w[1], w[2], w[3]);
    } else if (jid < 3136) {               // awfrag: 4 otiles x 2 chalf x 64
        const int e = jid - 2624;
        const int ot = e >> 7, ch = (e >> 6) & 1, lane = e & 63;
        const int col = lane & 15, quad = lane >> 4;
        const int o = ot * 16 + col;
        const float sc = bn_g[o] * rsqrtf(bn_v[o] + EPS);
        unsigned w[4];
        #pragma unroll
        for (int j2 = 0; j2 < 4; ++j2) {
            const int c = ch * 32 + quad * 8 + 2 * j2;
            w[j2] = pk2(attn_w[o * 64 + c] * sc, attn_w[o * 64 + c + 1] * sc);
        }
        *(uint4*)&W[WS_AWF + (ot * 2 + ch) * 256 + lane * 4] = make_uint4(w[0], w[1], w[2], w[3]);
    } else if (jid < 3200) {               // aoff
        const int o = jid - 3136;
        const float sc = bn_g[o] * rsqrtf(bn_v[o] + EPS);
        ((float*)(W + WS_AOFF))[o] = attn_b[o] * sc + bn_b[o] - bn_m[o] * sc;
    } else if (jid < 3264) {               // scO
        const int o = jid - 3200;
        ((float*)(W + WS_SCO))[o] = bn_g[o] * rsqrtf(bn_v[o] + EPS);
    } else if (jid < 4800) {               // wfrag: 12 otiles x 2 chalf x 64
        const int e = jid - 3264;
        const int ot = e >> 7, ch = (e >> 6) & 1, lane = e & 63;
        const int col = lane & 15, quad = lane >> 4;
        const int o = ot * 16 + col;
        const float qs = (o < 64) ? 0.25f * LOG2E : 1.f;
        unsigned w[4];
        #pragma unroll
        for (int j2 = 0; j2 < 4; ++j2) {
            const int c = ch * 32 + quad * 8 + 2 * j2;
            w[j2] = pk2(qkv_w[o * 64 + c] * qs, qkv_w[o * 64 + c + 1] * qs);
        }
        *(uint4*)&W[WS_WFRAG + (ot * 2 + ch) * 256 + lane * 4] = make_uint4(w[0], w[1], w[2], w[3]);
    } else if (jid < 4992) {               // qb2
        const int o = jid - 4800;
        ((float*)(W + WS_QB2))[o] = qkv_b[o] * ((o < 64) ? 0.25f * LOG2E : 1.f);
    } else if (jid < 6592) {               // data_bn sc/sh per (c*25+v)
        const int e = jid - 4992;
        const float sc = dbn_g[e] * rsqrtf(dbn_v[e] + EPS);
        const float sh = dbn_b[e] - dbn_m[e] * sc;
        ((float2*)(W + WS_SCSH))[e] = make_float2(sc, sh);
    }
}

// ---------------------------------------------------------------------------
// k_qkv (MFMA): per (t-tile, n), 512 thr. float4 coalesced x loads, data_bn
// applied in staging (scsh fmaf from LDS table); shared weight B-frags loaded
// ONCE per wave.
// ---------------------------------------------------------------------------
__global__ __launch_bounds__(512) void k_qkv(
        const float* __restrict__ x, unsigned* __restrict__ W)
{
    const int tt = blockIdx.x, n = blockIdx.y, t0 = tt * 16;
    const int tid = threadIdx.x;
    const unsigned* wfrag = W + WS_WFRAG;
    const float* qb2 = (const float*)(W + WS_QB2);
    unsigned* qk_p = W + WS_QK;
    unsigned* v_p  = W + WS_V;

    __shared__ unsigned afrag[25 * 516];   // 51.6 KB
    __shared__ float2 sls[1600];           // 12.8 KB data_bn (sc,sh) table

    for (int i = tid; i < 1600; i += 512)
        sls[i] = ((const float2*)(W + WS_SCSH))[i];
    __syncthreads();

    // stage: 3200 jobs = 32 c-pairs x 100 float4 (contiguous flat = t*25+v)
    for (int i = tid; i < 3200; i += 512) {
        const int f4 = i % 100, cp = i / 100;
        const int c0 = cp * 2;
        float4 xa = make_float4(0.f, 0.f, 0.f, 0.f);
        float4 xb = make_float4(0.f, 0.f, 0.f, 0.f);
        if (tt < 18 || f4 < 75) {          // tail tile: only 300 floats valid
            const float* p = x + (size_t)(n * 64 + c0) * 7500 + tt * 400 + f4 * 4;
            xa = *(const float4*)p;
            xb = *(const float4*)(p + 7500);
        }
        const int ch = cp >> 4, qd = (cp >> 2) & 3, j2 = cp & 3;
        const float ea[4] = {xa.x, xa.y, xa.z, xa.w};
        const float eb[4] = {xb.x, xb.y, xb.z, xb.w};
        #pragma unroll
        for (int e = 0; e < 4; ++e) {
            const int flat = f4 * 4 + e;
            const int tl = (flat * 5243) >> 17;     // flat / 25
            const int v  = flat - 25 * tl;
            const float2 s0 = sls[c0 * 25 + v];
            const float2 s1 = sls[c0 * 25 + 25 + v];
            const float a0 = fmaf(ea[e], s0.x, s0.y);
            const float a1 = fmaf(eb[e], s1.x, s1.y);
            afrag[v * 516 + (ch * 64 + qd * 16 + tl) * 4 + j2] = pk2(a0, a1);
        }
    }
    __syncthreads();

    const int wvv = tid >> 6, lane = tid & 63, col = lane & 15, quad = lane >> 4;
    const int otg = wvv >> 1, vh = wvv & 1;
    const int vlo = 13 * vh, vhi = vh ? 25 : 13;
    const float4v zero4 = {0.f, 0.f, 0.f, 0.f};
    const bool tvalid = (t0 + 4 * quad + 3 < TT);

    U8 bf[3][2]; float qb_l[3];
    #pragma unroll
    for (int i = 0; i < 3; ++i) {
        const int ot = 3 * otg + i;
        #pragma unroll
        for (int ch = 0; ch < 2; ++ch) {
            const uint4 u = *(const uint4*)&wfrag[(ot * 2 + ch) * 256 + lane * 4];
            bf[i][ch].w[0] = u.x; bf[i][ch].w[1] = u.y; bf[i][ch].w[2] = u.z; bf[i][ch].w[3] = u.w;
        }
        qb_l[i] = qb2[ot * 16 + col];
    }

    for (int v = vlo; v < vhi; ++v) {
        const int b = n * 25 + v;
        U8 a0, a1;
        { const uint4 u = *(const uint4*)&afrag[v * 516 + lane * 4];
          a0.w[0] = u.x; a0.w[1] = u.y; a0.w[2] = u.z; a0.w[3] = u.w; }
        { const uint4 u = *(const uint4*)&afrag[v * 516 + 256 + lane * 4];
          a1.w[0] = u.x; a1.w[1] = u.y; a1.w[2] = u.z; a1.w[3] = u.w; }
        #pragma unroll
        for (int i = 0; i < 3; ++i) {
            const int ot = 3 * otg + i;
            float4v acc = __builtin_amdgcn_mfma_f32_16x16x32_bf16(a0.v, bf[i][0].v, zero4, 0, 0, 0);
            acc = __builtin_amdgcn_mfma_f32_16x16x32_bf16(a1.v, bf[i][1].v, acc, 0, 0, 0);
            float val[4];
            #pragma unroll
            for (int r = 0; r < 4; ++r) val[r] = acc[r] + qb_l[i];
            if (ot < 8) {                  // q|k: pair neighbor o lanes
                unsigned pk[4];
                #pragma unroll
                for (int r = 0; r < 4; ++r) {
                    const float p = __shfl_xor(val[r], 1);
                    pk[r] = pk2(val[r], p);
                }
                if (((col & 1) == 0) && tvalid) {
                    const int op = ot * 8 + (col >> 1);
                    *(uint4*)&qk_p[(size_t)(b * 64 + op) * TT + t0 + 4 * quad] =
                        make_uint4(pk[0], pk[1], pk[2], pk[3]);
                }
            } else {                       // v: pair along t; zero-fill t>=300
                const int d = (ot - 8) * 16 + col;
                uint2 u;
                if (tvalid) { u.x = pk2(val[0], val[1]); u.y = pk2(val[2], val[3]); }
                else        { u.x = 0u; u.y = 0u; }
                *(uint2*)&v_p[(size_t)(b * 64 + d) * 152 + 8 * tt + 2 * quad] = u;
            }
        }
    }
}

// ---------------------------------------------------------------------------
// k_attn: ONE block per (b,h) (grid 1600, 4 waves), tiles strided by 4.
// kbuf/vbuf staged once. Aligned s-ring b128 reads on the QK critical path.
// Ring writes LINEAR into the 68-slot row pad (mergeable ds_write2_b32,
// max index 66 never read) + rare exec-masked wrap fixup. Unroll-3 pipeline.
// ---------------------------------------------------------------------------
__global__ __launch_bounds__(256, 4) void k_attn(unsigned* __restrict__ W)
{
    const int bh = blockIdx.x;             // 0..1599
    const int b = bh >> 2, h = bh & 3;
    const int tid  = threadIdx.x;
    const int wave = tid >> 6, lane = tid & 63;
    const int col  = lane & 15, quad = lane >> 4;

    const unsigned* qk_p = W + WS_QK;
    const unsigned* v_p  = W + WS_V;
    unsigned* ah_p = W + WS_AH;
    const unsigned* relfrag = W + WS_REL;

    __shared__ unsigned kbuf[19 * 32 * 4];   // 9.7 KB
    __shared__ unsigned vbuf[10 * 64 * 4];   // 10.2 KB (s-permuted)
    __shared__ float relbuf[4][16 * 68];     // per-wave s-ring (64 slots + pad)

    for (int p = tid; p < 2432; p += 256) {
        const int c = p & 15, j2 = (p >> 4) & 3, qh = (p >> 6) & 1, st = p >> 7;
        kbuf[(st * 32 + qh * 16 + c) * 4 + j2] =
            qk_p[(size_t)(b * 64 + 32 + h * 8 + qh * 4 + j2) * TT + st * 16 + c];
    }
    // V staging with k<->s permutation: quad q of the PV A/B frag owns
    // s-pairs {2q, 2q+1, 8+2q, 8+2q+1} within each 32-s chunk.
    for (int p = tid; p < 640; p += 256) {
        const int tq = p % 40, d = p / 40;
        const int off = (tq * 4 <= 148) ? tq * 4 : 144;  // clamp (slots unused)
        const uint4 u = *(const uint4*)&v_p[(size_t)(b * 64 + h * 16 + d) * 152 + off];
        const int c = tq >> 2;
        const int l0 = (tq & 3) * 4;
        const unsigned uu[4] = {u.x, u.y, u.z, u.w};
        #pragma unroll
        for (int j = 0; j < 4; ++j) {
            const int local = l0 + j;
            const int q  = (local < 8) ? (local >> 1) : ((local - 8) >> 1);
            const int j2 = (local < 8) ? (local & 1) : (2 + (local & 1));
            vbuf[(c * 64 + q * 16 + d) * 4 + j2] = uu[j];
        }
    }
    __syncthreads();

    float* relw = &relbuf[wave][0];
    const float4v zero4 = {0.f, 0.f, 0.f, 0.f};
    U8 onef;
    onef.w[0] = onef.w[1] = onef.w[2] = onef.w[3] = 0x3F803F80u;

    for (int tt = wave; tt < 19; tt += 4) {
        const int t0 = tt * 16;

        // ---- Q B-frag (cols = t) ----
        U8 qf;
        if (quad < 2) {
            int t = t0 + col; if (t > TT - 1) t = TT - 1;
            const size_t rb = (size_t)(b * 64 + h * 8 + quad * 4) * TT + t;
            qf.w[0] = qk_p[rb];
            qf.w[1] = qk_p[rb + TT];
            qf.w[2] = qk_p[rb + 2 * TT];
            qf.w[3] = qk_p[rb + 3 * TT];
        } else {
            qf.w[0] = qf.w[1] = qf.w[2] = qf.w[3] = 0u;
        }

        auto rel_ld = [&](int mt) -> uint4 {
            return *(const uint4*)&relfrag[(mt + 1) * 256 + lane * 4];
        };
        // s-ring write: slot(s) = (m + t - 299) mod 64. Write LINEARLY at
        // wb..wb+3 (row has 68 slots; wb<=63 so max index 66, never read)
        // -> compiler merges into ds_write2_b32 pairs. Elements that
        // logically wrap (wb+j >= 64, only when wb > 60) also land at their
        // logical slot via a rare exec-masked fixup.
        auto rel_do = [&](int mt, uint4 u) {
            U8 kr; kr.w[0] = u.x; kr.w[1] = u.y; kr.w[2] = u.z; kr.w[3] = u.w;
            const float4v rc = __builtin_amdgcn_mfma_f32_16x16x32_bf16(
                                   kr.v, qf.v, zero4, 0, 0, 0);
            const int wb = (mt * 16 + 4 * quad + t0 + col + 21) & 63;
            float* rw = &relw[col * 68 + wb];
            rw[0] = rc[0]; rw[1] = rc[1]; rw[2] = rc[2]; rw[3] = rc[3];
            if (wb > 60) {
                #pragma unroll
                for (int j = 1; j < 4; ++j)
                    if (wb + j >= 64) relw[col * 68 + wb + j - 64] = rc[j];
            }
        };

        #pragma unroll
        for (int i = 0; i < 4; ++i) rel_do(17 - tt + i, rel_ld(17 - tt + i));
        uint4 ru0 = rel_ld(21 - tt), ru1 = rel_ld(22 - tt);

        float4v accPV = zero4;
        float4v accS  = zero4;

        #pragma unroll 3
        for (int c = 0; c < 9; ++c) {       // chunks of 2 s-tiles: s 0..287
            U8 kf0, kf1;
            if (quad < 2) {
                const uint4 u0 = *(const uint4*)&kbuf[((2 * c) * 32 + quad * 16 + col) * 4];
                const uint4 u1 = *(const uint4*)&kbuf[((2 * c + 1) * 32 + quad * 16 + col) * 4];
                kf0.w[0] = u0.x; kf0.w[1] = u0.y; kf0.w[2] = u0.z; kf0.w[3] = u0.w;
                kf1.w[0] = u1.x; kf1.w[1] = u1.y; kf1.w[2] = u1.z; kf1.w[3] = u1.w;
            } else {
                kf0.w[0] = kf0.w[1] = kf0.w[2] = kf0.w[3] = 0u;
                kf1.w[0] = kf1.w[1] = kf1.w[2] = kf1.w[3] = 0u;
            }
            const short8 vf = *(const short8*)&vbuf[(c * 64 + lane) * 4];

            // aligned s-ring reads: rows s = 32c+4q+r (qk0), +16 (qk1)
            const int rb0 = (32 * c + 4 * quad) & 63;
            const float4v rc0 = *(const float4v*)&relw[col * 68 + rb0];
            const float4v rc1 = *(const float4v*)&relw[col * 68 + ((rb0 + 16) & 63)];
            const float4v qk0 = __builtin_amdgcn_mfma_f32_16x16x32_bf16(kf0.v, qf.v, rc0, 0, 0, 0);
            const float4v qk1 = __builtin_amdgcn_mfma_f32_16x16x32_bf16(kf1.v, qf.v, rc1, 0, 0, 0);

            const float e0 = ex2(qk0[0]);
            const float e1 = ex2(qk0[1]);
            const float e2 = ex2(qk0[2]);
            const float e3 = ex2(qk0[3]);
            const float e4 = ex2(qk1[0]);
            const float e5 = ex2(qk1[1]);
            const float e6 = ex2(qk1[2]);
            const float e7 = ex2(qk1[3]);

            U8 pf;
            pf.w[0] = pk2(e0, e1);
            pf.w[1] = pk2(e2, e3);
            pf.w[2] = pk2(e4, e5);
            pf.w[3] = pk2(e6, e7);
            accPV = __builtin_amdgcn_mfma_f32_16x16x32_bf16(pf.v, vf, accPV, 0, 0, 0);
            accS  = __builtin_amdgcn_mfma_f32_16x16x32_bf16(pf.v, onef.v, accS, 0, 0, 0);

            rel_do(2 * c + 21 - tt, ru0);
            rel_do(2 * c + 22 - tt, ru1);
            if (c < 8) { ru0 = rel_ld(2 * c + 23 - tt); ru1 = rel_ld(2 * c + 24 - tt); }
        }

        // ---- tail chunk 9: stile 18 only (s 288..303; s>=300 masked) ----
        {
            U8 kf0;
            if (quad < 2) {
                const uint4 u0 = *(const uint4*)&kbuf[(18 * 32 + quad * 16 + col) * 4];
                kf0.w[0] = u0.x; kf0.w[1] = u0.y; kf0.w[2] = u0.z; kf0.w[3] = u0.w;
            } else {
                kf0.w[0] = kf0.w[1] = kf0.w[2] = kf0.w[3] = 0u;
            }
            const int rb0 = (288 + 4 * quad) & 63;
            const float4v rc0 = *(const float4v*)&relw[col * 68 + rb0];
            const float4v qk0 = __builtin_amdgcn_mfma_f32_16x16x32_bf16(kf0.v, qf.v, rc0, 0, 0, 0);
            float e0 = ex2(qk0[0]);
            float e1 = ex2(qk0[1]);
            float e2 = ex2(qk0[2]);
            float e3 = ex2(qk0[3]);
            if (quad == 3) { e0 = e1 = e2 = e3 = 0.f; }
            U8 pf;
            pf.w[0] = pk2(e0, e1);
            pf.w[1] = pk2(e2, e3);
            pf.w[2] = 0u;
            pf.w[3] = 0u;
            const short8 vf = *(const short8*)&vbuf[(9 * 64 + lane) * 4];
            accPV = __builtin_amdgcn_mfma_f32_16x16x32_bf16(pf.v, vf, accPV, 0, 0, 0);
            accS  = __builtin_amdgcn_mfma_f32_16x16x32_bf16(pf.v, onef.v, accS, 0, 0, 0);
        }

        // ---- finalize: accS holds per-lane row sums (t = 4*quad+r) ----
        if (t0 + 4 * quad + 3 < TT) {
            uint2 u;
            u.x = pk2(accPV[0] * rcpf_(accS[0]), accPV[1] * rcpf_(accS[1]));
            u.y = pk2(accPV[2] * rcpf_(accS[2]), accPV[3] * rcpf_(accS[3]));
            *(uint2*)&ah_p[(size_t)(b * 64 + h * 16 + col) * 152 + 8 * tt + 2 * quad] = u;
        }
    }
}

// ---------------------------------------------------------------------------
// k_out (MFMA): per (t-tile, n, t-quarter), 512 thr (waves = otile x t-half).
// x and out through LDS flat buffers (float4-coalesced global traffic).
// ---------------------------------------------------------------------------
__global__ __launch_bounds__(512) void k_out(
        const float* __restrict__ x, const unsigned* __restrict__ W,
        float* __restrict__ out)
{
    const int tt = blockIdx.x, n = blockIdx.y, tq = blockIdx.z;
    if (tt == 18 && tq == 3) return;
    const int t0q = tt * 16 + tq * 4;
    const int tid = threadIdx.x;
    const unsigned* ah_p = W + WS_AH;
    const unsigned* awfrag = W + WS_AWF;
    const float* aoff = (const float*)(W + WS_AOFF);
    const float* scO  = (const float*)(W + WS_SCO);

    __shared__ unsigned fbuf[4 * 1024];    // 16 KB (ah A-frags)
    __shared__ float obuf[6400];           // 25.6 KB (x tile, then out tile)

    // stage x tile (64 o x 4 t x 25 v) via flat float4 (fully coalesced)
    for (int j = tid; j < 1600; j += 512) {
        const int o = j / 25, f4 = j - 25 * o;
        const float4 xv = *(const float4*)(x + (size_t)(n * 64 + o) * 7500 + t0q * 25 + f4 * 4);
        *(float4*)&obuf[o * 100 + f4 * 4] = xv;
    }
    // stage ah A-frags
    for (int i = tid; i < 1600; i += 512) {
        const int tp2 = i & 1, pc = (i >> 1) & 31, v = i >> 6;
        const int b = n * 25 + v;
        const size_t r0 = (size_t)(b * 64 + 2 * pc) * 152 + tt * 8 + tq * 2 + tp2;
        const unsigned A = ah_p[r0], Bv = ah_p[r0 + 152];
        const unsigned ue = (A & 0xFFFFu) | (Bv << 16);
        const unsigned uo = (A >> 16) | (Bv & 0xFFFF0000u);
        const int vt = v >> 4, cv = v & 15, ch = pc >> 4, qd = (pc >> 2) & 3, j2 = pc & 3;
        const int xi = (vt * 2 + ch) * 256 + (qd * 16 + (cv ^ qd)) * 4 + j2;
        const int tl = 2 * tp2;
        fbuf[tl * 1024 + ((xi + 12 * tl) & 1023)]             = ue;
        fbuf[(tl + 1) * 1024 + ((xi + 12 * (tl + 1)) & 1023)] = uo;
    }
    __syncthreads();

    const int wv = tid >> 6, lane = tid & 63, col = lane & 15, quad = lane >> 4;
    const int ow = wv & 3, th = wv >> 2;
    const int o = ow * 16 + col;
    const float4v zero4 = {0.f, 0.f, 0.f, 0.f};

    U8 awf0, awf1;
    { const uint4 u = *(const uint4*)&awfrag[(ow * 2 + 0) * 256 + lane * 4];
      awf0.w[0] = u.x; awf0.w[1] = u.y; awf0.w[2] = u.z; awf0.w[3] = u.w; }
    { const uint4 u = *(const uint4*)&awfrag[(ow * 2 + 1) * 256 + lane * 4];
      awf1.w[0] = u.x; awf1.w[1] = u.y; awf1.w[2] = u.z; awf1.w[3] = u.w; }
    const float aoff_l = aoff[o], sc_l = scO[o];

    for (int tl = 2 * th; tl < 2 * th + 2; ++tl) {
        #pragma unroll
        for (int vt = 0; vt < 2; ++vt) {
            U8 a0, a1;
            { const int xb = (vt * 2 + 0) * 256 + (quad * 16 + (col ^ quad)) * 4;
              const uint4 u = *(const uint4*)&fbuf[tl * 1024 + ((xb + 12 * tl) & 1023)];
              a0.w[0] = u.x; a0.w[1] = u.y; a0.w[2] = u.z; a0.w[3] = u.w; }
            { const int xb = (vt * 2 + 1) * 256 + (quad * 16 + (col ^ quad)) * 4;
              const uint4 u = *(const uint4*)&fbuf[tl * 1024 + ((xb + 12 * tl) & 1023)];
              a1.w[0] = u.x; a1.w[1] = u.y; a1.w[2] = u.z; a1.w[3] = u.w; }
            float4v acc = __builtin_amdgcn_mfma_f32_16x16x32_bf16(a0.v, awf0.v, zero4, 0, 0, 0);
            acc = __builtin_amdgcn_mfma_f32_16x16x32_bf16(a1.v, awf1.v, acc, 0, 0, 0);
            #pragma unroll
            for (int r = 0; r < 4; ++r) {
                const int v = vt * 16 + 4 * quad + r;
                if (v < 25) {
                    const int oi = o * 100 + tl * 25 + v;
                    obuf[oi] = fmaxf(fmaf(obuf[oi], sc_l, acc[r] + aoff_l), 0.f);
                }
            }
        }
    }
    __syncthreads();

    // flush out tile via flat float4 (fully coalesced)
    for (int j = tid; j < 1600; j += 512) {
        const int o2 = j / 25, f4 = j - 25 * o2;
        *(float4*)(out + (size_t)(n * 64 + o2) * 7500 + t0q * 25 + f4 * 4) =
            *(const float4*)&obuf[o2 * 100 + f4 * 4];
    }
}

// ---------------------------------------------------------------------------
extern "C" void kernel_launch(void* const* d_in, const int* in_sizes, int n_in,
                              void* d_out, int out_size, void* d_ws, size_t ws_size,
                              hipStream_t stream)
{
    const float* x       = (const float*)d_in[0];
    const float* dbn_g   = (const float*)d_in[1];
    const float* dbn_b   = (const float*)d_in[2];
    const float* dbn_m   = (const float*)d_in[3];
    const float* dbn_v   = (const float*)d_in[4];
    const float* qkv_w   = (const float*)d_in[5];
    const float* qkv_b   = (const float*)d_in[6];
    const float* key_rel = (const float*)d_in[7];
    const float* attn_w  = (const float*)d_in[8];
    const float* attn_b  = (const float*)d_in[9];
    const float* bn_g    = (const float*)d_in[10];
    const float* bn_b    = (const float*)d_in[11];
    const float* bn_m    = (const float*)d_in[12];
    const float* bn_v    = (const float*)d_in[13];
    float* out = (float*)d_out;
    unsigned* W = (unsigned*)d_ws;

    k_pre<<<26, 256, 0, stream>>>(dbn_g, dbn_b, dbn_m, dbn_v, qkv_w, qkv_b,
                                  key_rel, attn_w, attn_b, bn_g, bn_b, bn_m,
                                  bn_v, W);
    k_qkv<<<dim3(19, 16), 512, 0, stream>>>(x, W);
    k_attn<<<1600, 256, 0, stream>>>(W);
    k_out<<<dim3(19, 16, 4), 512, 0, stream>>>(x, W, out);
}

// Round 8
// 233.946 us; speedup vs baseline: 1.0210x; 1.0210x over previous
//
#include <hip/hip_runtime.h>
#include <hip/hip_bf16.h>
#include <cstddef>

// Problem constants
#define NN 16
#define CC 64
#define TT 300
#define VV 25
#define NHH 4
#define DKHH 16
#define BB (NN * VV)          // 400
#define EPS 1e-5f
#define LOG2E 1.4426950408889634f

// Workspace layout (u32 units)
#define WS_QK    0            // u32[400][64][300]  q|k bf16, paired along o (q pre-scaled 0.25*log2e)
#define WS_V     7680000      // u32[400][64][152]  v bf16, paired along t (t>=300 zero-filled)
#define WS_AH    11571200     // u32[400][64][152]  attnh bf16, paired along t
#define WS_REL   15462400     // u32[41][64][4] key_rel frags (slot = mtile+1, slot0 = zeros)
#define WS_AWF   15472896     // u32[4][2][64][4] attn_w B-frags (pre-scaled by bn scale)
#define WS_AOFF  15474944     // f32[64] fused attn_b+bn offset
#define WS_SCO   15475008     // f32[64] bn scale (for skip path)
#define WS_WFRAG 15475072     // u32[12][2][64][4] qkv_w B-frags (q pre-scaled 0.25*log2e)
#define WS_QB2   15481216     // f32[192] qkv_b (q pre-scaled)
#define WS_SCSH  15481408     // float2[1600] data_bn (sc, sh) per (c, v)

typedef __attribute__((ext_vector_type(8))) short short8;
typedef __attribute__((ext_vector_type(4))) float float4v;

union U8 { short8 v; unsigned int w[4]; };

// f32x2 -> packed bf16x2 (RNE). HW op if available, else manual.
__device__ __forceinline__ unsigned int pk2(float a, float b) {
#if __has_builtin(__builtin_amdgcn_cvt_pk_bf16_f32)
    typedef __attribute__((ext_vector_type(2))) __bf16 bf2;
    union { bf2 v; unsigned u; } c;
    c.v = __builtin_amdgcn_cvt_pk_bf16_f32(a, b);
    return c.u;
#else
    union { float f; unsigned u; } x, y;
    x.f = a; y.f = b;
    unsigned ua = x.u + 0x7FFFu + ((x.u >> 16) & 1u);
    unsigned ub = y.u + 0x7FFFu + ((y.u >> 16) & 1u);
    return (ua >> 16) | (ub & 0xFFFF0000u);
#endif
}

__device__ __forceinline__ float ex2(float x) {
#if __has_builtin(__builtin_amdgcn_exp2f)
    return __builtin_amdgcn_exp2f(x);
#else
    return exp2f(x);
#endif
}

__device__ __forceinline__ float rcpf_(float x) {
#if __has_builtin(__builtin_amdgcn_rcpf)
    return __builtin_amdgcn_rcpf(x);
#else
    return 1.f / x;
#endif
}

// ---------------------------------------------------------------------------
// k_pre: constant tables.
// ---------------------------------------------------------------------------
__global__ __launch_bounds__(256) void k_pre(
    const float* __restrict__ dbn_g, const float* __restrict__ dbn_b,
    const float* __restrict__ dbn_m, const float* __restrict__ dbn_v,
    const float* __restrict__ qkv_w, const float* __restrict__ qkv_b,
    const float* __restrict__ key_rel,
    const float* __restrict__ attn_w, const float* __restrict__ attn_b,
    const float* __restrict__ bn_g, const float* __restrict__ bn_b,
    const float* __restrict__ bn_m, const float* __restrict__ bn_v,
    unsigned* __restrict__ W)
{
    const int jid = blockIdx.x * 256 + threadIdx.x;
    if (jid < 2624) {                      // relfrag: 41 slots x 64 lanes
        const int k = jid >> 6, lane = jid & 63, col = lane & 15, quad = lane >> 4;
        const int mt = k - 1, m = mt * 16 + col;
        const bool ok = (quad < 2) && (mt >= 0) && (m < 2 * TT - 1);
        unsigned w[4];
        #pragma unroll
        for (int j2 = 0; j2 < 4; ++j2) {
            const int c = quad * 8 + 2 * j2;
            const float v0 = ok ? key_rel[m * 16 + c] : 0.f;
            const float v1 = ok ? key_rel[m * 16 + c + 1] : 0.f;
            w[j2] = pk2(v0, v1);
        }
        *(uint4*)&W[WS_REL + k * 256 + lane * 4] = make_uint4(w[0], w[1], w[2], w[3]);
    } else if (jid < 3136) {               // awfrag: 4 otiles x 2 chalf x 64
        const int e = jid - 2624;
        const int ot = e >> 7, ch = (e >> 6) & 1, lane = e & 63;
        const int col = lane & 15, quad = lane >> 4;
        const int o = ot * 16 + col;
        const float sc = bn_g[o] * rsqrtf(bn_v[o] + EPS);
        unsigned w[4];
        #pragma unroll
        for (int j2 = 0; j2 < 4; ++j2) {
            const int c = ch * 32 + quad * 8 + 2 * j2;
            w[j2] = pk2(attn_w[o * 64 + c] * sc, attn_w[o * 64 + c + 1] * sc);
        }
        *(uint4*)&W[WS_AWF + (ot * 2 + ch) * 256 + lane * 4] = make_uint4(w[0], w[1], w[2], w[3]);
    } else if (jid < 3200) {               // aoff
        const int o = jid - 3136;
        const float sc = bn_g[o] * rsqrtf(bn_v[o] + EPS);
        ((float*)(W + WS_AOFF))[o] = attn_b[o] * sc + bn_b[o] - bn_m[o] * sc;
    } else if (jid < 3264) {               // scO
        const int o = jid - 3200;
        ((float*)(W + WS_SCO))[o] = bn_g[o] * rsqrtf(bn_v[o] + EPS);
    } else if (jid < 4800) {               // wfrag: 12 otiles x 2 chalf x 64
        const int e = jid - 3264;
        const int ot = e >> 7, ch = (e >> 6) & 1, lane = e & 63;
        const int col = lane & 15, quad = lane >> 4;
        const int o = ot * 16 + col;
        const float qs = (o < 64) ? 0.25f * LOG2E : 1.f;
        unsigned w[4];
        #pragma unroll
        for (int j2 = 0; j2 < 4; ++j2) {
            const int c = ch * 32 + quad * 8 + 2 * j2;
            w[j2] = pk2(qkv_w[o * 64 + c] * qs, qkv_w[o * 64 + c + 1] * qs);
        }
        *(uint4*)&W[WS_WFRAG + (ot * 2 + ch) * 256 + lane * 4] = make_uint4(w[0], w[1], w[2], w[3]);
    } else if (jid < 4992) {               // qb2
        const int o = jid - 4800;
        ((float*)(W + WS_QB2))[o] = qkv_b[o] * ((o < 64) ? 0.25f * LOG2E : 1.f);
    } else if (jid < 6592) {               // data_bn sc/sh per (c*25+v)
        const int e = jid - 4992;
        const float sc = dbn_g[e] * rsqrtf(dbn_v[e] + EPS);
        const float sh = dbn_b[e] - dbn_m[e] * sc;
        ((float2*)(W + WS_SCSH))[e] = make_float2(sc, sh);
    }
}

// ---------------------------------------------------------------------------
// k_qkv (MFMA): per (t-tile, n), 1024 thr (16 waves = 4 otg x 4 v-quarter).
// Doubled wave residency vs the 512-thr version (~2.4 -> ~4.8 waves/SIMD at
// 1.19 blocks/CU) to hide staging-load and MFMA latency. Same LDS, same work.
// ---------------------------------------------------------------------------
__global__ __launch_bounds__(1024) void k_qkv(
        const float* __restrict__ x, unsigned* __restrict__ W)
{
    const int tt = blockIdx.x, n = blockIdx.y, t0 = tt * 16;
    const int tid = threadIdx.x;
    const unsigned* wfrag = W + WS_WFRAG;
    const float* qb2 = (const float*)(W + WS_QB2);
    unsigned* qk_p = W + WS_QK;
    unsigned* v_p  = W + WS_V;

    __shared__ unsigned afrag[25 * 516];   // 51.6 KB
    __shared__ float2 sls[1600];           // 12.8 KB data_bn (sc,sh) table

    for (int i = tid; i < 1600; i += 1024)
        sls[i] = ((const float2*)(W + WS_SCSH))[i];
    __syncthreads();

    // stage: 3200 jobs = 32 c-pairs x 100 float4 (contiguous flat = t*25+v)
    for (int i = tid; i < 3200; i += 1024) {
        const int f4 = i % 100, cp = i / 100;
        const int c0 = cp * 2;
        float4 xa = make_float4(0.f, 0.f, 0.f, 0.f);
        float4 xb = make_float4(0.f, 0.f, 0.f, 0.f);
        if (tt < 18 || f4 < 75) {          // tail tile: only 300 floats valid
            const float* p = x + (size_t)(n * 64 + c0) * 7500 + tt * 400 + f4 * 4;
            xa = *(const float4*)p;
            xb = *(const float4*)(p + 7500);
        }
        const int ch = cp >> 4, qd = (cp >> 2) & 3, j2 = cp & 3;
        const float ea[4] = {xa.x, xa.y, xa.z, xa.w};
        const float eb[4] = {xb.x, xb.y, xb.z, xb.w};
        #pragma unroll
        for (int e = 0; e < 4; ++e) {
            const int flat = f4 * 4 + e;
            const int tl = (flat * 5243) >> 17;     // flat / 25
            const int v  = flat - 25 * tl;
            const float2 s0 = sls[c0 * 25 + v];
            const float2 s1 = sls[c0 * 25 + 25 + v];
            const float a0 = fmaf(ea[e], s0.x, s0.y);
            const float a1 = fmaf(eb[e], s1.x, s1.y);
            afrag[v * 516 + (ch * 64 + qd * 16 + tl) * 4 + j2] = pk2(a0, a1);
        }
    }
    __syncthreads();

    const int wvv = tid >> 6, lane = tid & 63, col = lane & 15, quad = lane >> 4;
    const int otg = wvv >> 2, vq = wvv & 3;
    const int vlo = (vq == 0) ? 0 : (1 + 6 * vq);   // 0,7,13,19
    const int vhi = 7 + 6 * vq;                      // 7,13,19,25
    const float4v zero4 = {0.f, 0.f, 0.f, 0.f};
    const bool tvalid = (t0 + 4 * quad + 3 < TT);

    U8 bf[3][2]; float qb_l[3];
    #pragma unroll
    for (int i = 0; i < 3; ++i) {
        const int ot = 3 * otg + i;
        #pragma unroll
        for (int ch = 0; ch < 2; ++ch) {
            const uint4 u = *(const uint4*)&wfrag[(ot * 2 + ch) * 256 + lane * 4];
            bf[i][ch].w[0] = u.x; bf[i][ch].w[1] = u.y; bf[i][ch].w[2] = u.z; bf[i][ch].w[3] = u.w;
        }
        qb_l[i] = qb2[ot * 16 + col];
    }

    for (int v = vlo; v < vhi; ++v) {
        const int b = n * 25 + v;
        U8 a0, a1;
        { const uint4 u = *(const uint4*)&afrag[v * 516 + lane * 4];
          a0.w[0] = u.x; a0.w[1] = u.y; a0.w[2] = u.z; a0.w[3] = u.w; }
        { const uint4 u = *(const uint4*)&afrag[v * 516 + 256 + lane * 4];
          a1.w[0] = u.x; a1.w[1] = u.y; a1.w[2] = u.z; a1.w[3] = u.w; }
        #pragma unroll
        for (int i = 0; i < 3; ++i) {
            const int ot = 3 * otg + i;
            float4v acc = __builtin_amdgcn_mfma_f32_16x16x32_bf16(a0.v, bf[i][0].v, zero4, 0, 0, 0);
            acc = __builtin_amdgcn_mfma_f32_16x16x32_bf16(a1.v, bf[i][1].v, acc, 0, 0, 0);
            float val[4];
            #pragma unroll
            for (int r = 0; r < 4; ++r) val[r] = acc[r] + qb_l[i];
            if (ot < 8) {                  // q|k: pair neighbor o lanes
                unsigned pk[4];
                #pragma unroll
                for (int r = 0; r < 4; ++r) {
                    const float p = __shfl_xor(val[r], 1);
                    pk[r] = pk2(val[r], p);
                }
                if (((col & 1) == 0) && tvalid) {
                    const int op = ot * 8 + (col >> 1);
                    *(uint4*)&qk_p[(size_t)(b * 64 + op) * TT + t0 + 4 * quad] =
                        make_uint4(pk[0], pk[1], pk[2], pk[3]);
                }
            } else {                       // v: pair along t; zero-fill t>=300
                const int d = (ot - 8) * 16 + col;
                uint2 u;
                if (tvalid) { u.x = pk2(val[0], val[1]); u.y = pk2(val[2], val[3]); }
                else        { u.x = 0u; u.y = 0u; }
                *(uint2*)&v_p[(size_t)(b * 64 + d) * 152 + 8 * tt + 2 * quad] = u;
            }
        }
    }
}

// ---------------------------------------------------------------------------
// k_attn: ONE block per (b,h) (grid 1600, 4 waves), tiles strided by 4.
// kbuf/vbuf staged once. Aligned s-ring b128 reads on the QK critical path.
// Ring writes in mod-form (R6 measured-best). Unroll-3 chunk pipeline.
// ---------------------------------------------------------------------------
__global__ __launch_bounds__(256, 4) void k_attn(unsigned* __restrict__ W)
{
    const int bh = blockIdx.x;             // 0..1599
    const int b = bh >> 2, h = bh & 3;
    const int tid  = threadIdx.x;
    const int wave = tid >> 6, lane = tid & 63;
    const int col  = lane & 15, quad = lane >> 4;

    const unsigned* qk_p = W + WS_QK;
    const unsigned* v_p  = W + WS_V;
    unsigned* ah_p = W + WS_AH;
    const unsigned* relfrag = W + WS_REL;

    __shared__ unsigned kbuf[19 * 32 * 4];   // 9.7 KB
    __shared__ unsigned vbuf[10 * 64 * 4];   // 10.2 KB (s-permuted)
    __shared__ float relbuf[4][16 * 68];     // per-wave s-ring (64 slots + pad)

    for (int p = tid; p < 2432; p += 256) {
        const int c = p & 15, j2 = (p >> 4) & 3, qh = (p >> 6) & 1, st = p >> 7;
        kbuf[(st * 32 + qh * 16 + c) * 4 + j2] =
            qk_p[(size_t)(b * 64 + 32 + h * 8 + qh * 4 + j2) * TT + st * 16 + c];
    }
    // V staging with k<->s permutation: quad q of the PV A/B frag owns
    // s-pairs {2q, 2q+1, 8+2q, 8+2q+1} within each 32-s chunk.
    for (int p = tid; p < 640; p += 256) {
        const int tq = p % 40, d = p / 40;
        const int off = (tq * 4 <= 148) ? tq * 4 : 144;  // clamp (slots unused)
        const uint4 u = *(const uint4*)&v_p[(size_t)(b * 64 + h * 16 + d) * 152 + off];
        const int c = tq >> 2;
        const int l0 = (tq & 3) * 4;
        const unsigned uu[4] = {u.x, u.y, u.z, u.w};
        #pragma unroll
        for (int j = 0; j < 4; ++j) {
            const int local = l0 + j;
            const int q  = (local < 8) ? (local >> 1) : ((local - 8) >> 1);
            const int j2 = (local < 8) ? (local & 1) : (2 + (local & 1));
            vbuf[(c * 64 + q * 16 + d) * 4 + j2] = uu[j];
        }
    }
    __syncthreads();

    float* relw = &relbuf[wave][0];
    const float4v zero4 = {0.f, 0.f, 0.f, 0.f};
    U8 onef;
    onef.w[0] = onef.w[1] = onef.w[2] = onef.w[3] = 0x3F803F80u;

    for (int tt = wave; tt < 19; tt += 4) {
        const int t0 = tt * 16;

        // ---- Q B-frag (cols = t) ----
        U8 qf;
        if (quad < 2) {
            int t = t0 + col; if (t > TT - 1) t = TT - 1;
            const size_t rb = (size_t)(b * 64 + h * 8 + quad * 4) * TT + t;
            qf.w[0] = qk_p[rb];
            qf.w[1] = qk_p[rb + TT];
            qf.w[2] = qk_p[rb + 2 * TT];
            qf.w[3] = qk_p[rb + 3 * TT];
        } else {
            qf.w[0] = qf.w[1] = qf.w[2] = qf.w[3] = 0u;
        }

        auto rel_ld = [&](int mt) -> uint4 {
            return *(const uint4*)&relfrag[(mt + 1) * 256 + lane * 4];
        };
        // s-ring write: slot(s) = (m + t - 299) mod 64, s = diag index.
        // lane holds R[m = mt*16+4q+r, t = t0+col]; -299 == +21 (mod 64).
        auto rel_do = [&](int mt, uint4 u) {
            U8 kr; kr.w[0] = u.x; kr.w[1] = u.y; kr.w[2] = u.z; kr.w[3] = u.w;
            const float4v rc = __builtin_amdgcn_mfma_f32_16x16x32_bf16(
                                   kr.v, qf.v, zero4, 0, 0, 0);
            const int wbase = mt * 16 + 4 * quad + t0 + col + 21;
            float* rw = &relw[col * 68];
            rw[wbase & 63]       = rc[0];
            rw[(wbase + 1) & 63] = rc[1];
            rw[(wbase + 2) & 63] = rc[2];
            rw[(wbase + 3) & 63] = rc[3];
        };

        #pragma unroll
        for (int i = 0; i < 4; ++i) rel_do(17 - tt + i, rel_ld(17 - tt + i));
        uint4 ru0 = rel_ld(21 - tt), ru1 = rel_ld(22 - tt);

        float4v accPV = zero4;
        float4v accS  = zero4;

        #pragma unroll 3
        for (int c = 0; c < 9; ++c) {       // chunks of 2 s-tiles: s 0..287
            U8 kf0, kf1;
            if (quad < 2) {
                const uint4 u0 = *(const uint4*)&kbuf[((2 * c) * 32 + quad * 16 + col) * 4];
                const uint4 u1 = *(const uint4*)&kbuf[((2 * c + 1) * 32 + quad * 16 + col) * 4];
                kf0.w[0] = u0.x; kf0.w[1] = u0.y; kf0.w[2] = u0.z; kf0.w[3] = u0.w;
                kf1.w[0] = u1.x; kf1.w[1] = u1.y; kf1.w[2] = u1.z; kf1.w[3] = u1.w;
            } else {
                kf0.w[0] = kf0.w[1] = kf0.w[2] = kf0.w[3] = 0u;
                kf1.w[0] = kf1.w[1] = kf1.w[2] = kf1.w[3] = 0u;
            }
            const short8 vf = *(const short8*)&vbuf[(c * 64 + lane) * 4];

            // aligned s-ring reads: rows s = 32c+4q+r (qk0), +16 (qk1)
            const int rb0 = (32 * c + 4 * quad) & 63;
            const float4v rc0 = *(const float4v*)&relw[col * 68 + rb0];
            const float4v rc1 = *(const float4v*)&relw[col * 68 + ((rb0 + 16) & 63)];
            const float4v qk0 = __builtin_amdgcn_mfma_f32_16x16x32_bf16(kf0.v, qf.v, rc0, 0, 0, 0);
            const float4v qk1 = __builtin_amdgcn_mfma_f32_16x16x32_bf16(kf1.v, qf.v, rc1, 0, 0, 0);

            const float e0 = ex2(qk0[0]);
            const float e1 = ex2(qk0[1]);
            const float e2 = ex2(qk0[2]);
            const float e3 = ex2(qk0[3]);
            const float e4 = ex2(qk1[0]);
            const float e5 = ex2(qk1[1]);
            const float e6 = ex2(qk1[2]);
            const float e7 = ex2(qk1[3]);

            U8 pf;
            pf.w[0] = pk2(e0, e1);
            pf.w[1] = pk2(e2, e3);
            pf.w[2] = pk2(e4, e5);
            pf.w[3] = pk2(e6, e7);
            accPV = __builtin_amdgcn_mfma_f32_16x16x32_bf16(pf.v, vf, accPV, 0, 0, 0);
            accS  = __builtin_amdgcn_mfma_f32_16x16x32_bf16(pf.v, onef.v, accS, 0, 0, 0);

            rel_do(2 * c + 21 - tt, ru0);
            rel_do(2 * c + 22 - tt, ru1);
            if (c < 8) { ru0 = rel_ld(2 * c + 23 - tt); ru1 = rel_ld(2 * c + 24 - tt); }
        }

        // ---- tail chunk 9: stile 18 only (s 288..303; s>=300 masked) ----
        {
            U8 kf0;
            if (quad < 2) {
                const uint4 u0 = *(const uint4*)&kbuf[(18 * 32 + quad * 16 + col) * 4];
                kf0.w[0] = u0.x; kf0.w[1] = u0.y; kf0.w[2] = u0.z; kf0.w[3] = u0.w;
            } else {
                kf0.w[0] = kf0.w[1] = kf0.w[2] = kf0.w[3] = 0u;
            }
            const int rb0 = (288 + 4 * quad) & 63;
            const float4v rc0 = *(const float4v*)&relw[col * 68 + rb0];
            const float4v qk0 = __builtin_amdgcn_mfma_f32_16x16x32_bf16(kf0.v, qf.v, rc0, 0, 0, 0);
            float e0 = ex2(qk0[0]);
            float e1 = ex2(qk0[1]);
            float e2 = ex2(qk0[2]);
            float e3 = ex2(qk0[3]);
            if (quad == 3) { e0 = e1 = e2 = e3 = 0.f; }
            U8 pf;
            pf.w[0] = pk2(e0, e1);
            pf.w[1] = pk2(e2, e3);
            pf.w[2] = 0u;
            pf.w[3] = 0u;
            const short8 vf = *(const short8*)&vbuf[(9 * 64 + lane) * 4];
            accPV = __builtin_amdgcn_mfma_f32_16x16x32_bf16(pf.v, vf, accPV, 0, 0, 0);
            accS  = __builtin_amdgcn_mfma_f32_16x16x32_bf16(pf.v, onef.v, accS, 0, 0, 0);
        }

        // ---- finalize: accS holds per-lane row sums (t = 4*quad+r) ----
        if (t0 + 4 * quad + 3 < TT) {
            uint2 u;
            u.x = pk2(accPV[0] * rcpf_(accS[0]), accPV[1] * rcpf_(accS[1]));
            u.y = pk2(accPV[2] * rcpf_(accS[2]), accPV[3] * rcpf_(accS[3]));
            *(uint2*)&ah_p[(size_t)(b * 64 + h * 16 + col) * 152 + 8 * tt + 2 * quad] = u;
        }
    }
}

// ---------------------------------------------------------------------------
// k_out (MFMA): per (t-tile, n, t-quarter), 512 thr (waves = otile x t-half).
// x and out through LDS flat buffers (float4-coalesced global traffic).
// ---------------------------------------------------------------------------
__global__ __launch_bounds__(512) void k_out(
        const float* __restrict__ x, const unsigned* __restrict__ W,
        float* __restrict__ out)
{
    const int tt = blockIdx.x, n = blockIdx.y, tq = blockIdx.z;
    if (tt == 18 && tq == 3) return;
    const int t0q = tt * 16 + tq * 4;
    const int tid = threadIdx.x;
    const unsigned* ah_p = W + WS_AH;
    const unsigned* awfrag = W + WS_AWF;
    const float* aoff = (const float*)(W + WS_AOFF);
    const float* scO  = (const float*)(W + WS_SCO);

    __shared__ unsigned fbuf[4 * 1024];    // 16 KB (ah A-frags)
    __shared__ float obuf[6400];           // 25.6 KB (x tile, then out tile)

    // stage x tile (64 o x 4 t x 25 v) via flat float4 (fully coalesced)
    for (int j = tid; j < 1600; j += 512) {
        const int o = j / 25, f4 = j - 25 * o;
        const float4 xv = *(const float4*)(x + (size_t)(n * 64 + o) * 7500 + t0q * 25 + f4 * 4);
        *(float4*)&obuf[o * 100 + f4 * 4] = xv;
    }
    // stage ah A-frags
    for (int i = tid; i < 1600; i += 512) {
        const int tp2 = i & 1, pc = (i >> 1) & 31, v = i >> 6;
        const int b = n * 25 + v;
        const size_t r0 = (size_t)(b * 64 + 2 * pc) * 152 + tt * 8 + tq * 2 + tp2;
        const unsigned A = ah_p[r0], Bv = ah_p[r0 + 152];
        const unsigned ue = (A & 0xFFFFu) | (Bv << 16);
        const unsigned uo = (A >> 16) | (Bv & 0xFFFF0000u);
        const int vt = v >> 4, cv = v & 15, ch = pc >> 4, qd = (pc >> 2) & 3, j2 = pc & 3;
        const int xi = (vt * 2 + ch) * 256 + (qd * 16 + (cv ^ qd)) * 4 + j2;
        const int tl = 2 * tp2;
        fbuf[tl * 1024 + ((xi + 12 * tl) & 1023)]             = ue;
        fbuf[(tl + 1) * 1024 + ((xi + 12 * (tl + 1)) & 1023)] = uo;
    }
    __syncthreads();

    const int wv = tid >> 6, lane = tid & 63, col = lane & 15, quad = lane >> 4;
    const int ow = wv & 3, th = wv >> 2;
    const int o = ow * 16 + col;
    const float4v zero4 = {0.f, 0.f, 0.f, 0.f};

    U8 awf0, awf1;
    { const uint4 u = *(const uint4*)&awfrag[(ow * 2 + 0) * 256 + lane * 4];
      awf0.w[0] = u.x; awf0.w[1] = u.y; awf0.w[2] = u.z; awf0.w[3] = u.w; }
    { const uint4 u = *(const uint4*)&awfrag[(ow * 2 + 1) * 256 + lane * 4];
      awf1.w[0] = u.x; awf1.w[1] = u.y; awf1.w[2] = u.z; awf1.w[3] = u.w; }
    const float aoff_l = aoff[o], sc_l = scO[o];

    for (int tl = 2 * th; tl < 2 * th + 2; ++tl) {
        #pragma unroll
        for (int vt = 0; vt < 2; ++vt) {
            U8 a0, a1;
            { const int xb = (vt * 2 + 0) * 256 + (quad * 16 + (col ^ quad)) * 4;
              const uint4 u = *(const uint4*)&fbuf[tl * 1024 + ((xb + 12 * tl) & 1023)];
              a0.w[0] = u.x; a0.w[1] = u.y; a0.w[2] = u.z; a0.w[3] = u.w; }
            { const int xb = (vt * 2 + 1) * 256 + (quad * 16 + (col ^ quad)) * 4;
              const uint4 u = *(const uint4*)&fbuf[tl * 1024 + ((xb + 12 * tl) & 1023)];
              a1.w[0] = u.x; a1.w[1] = u.y; a1.w[2] = u.z; a1.w[3] = u.w; }
            float4v acc = __builtin_amdgcn_mfma_f32_16x16x32_bf16(a0.v, awf0.v, zero4, 0, 0, 0);
            acc = __builtin_amdgcn_mfma_f32_16x16x32_bf16(a1.v, awf1.v, acc, 0, 0, 0);
            #pragma unroll
            for (int r = 0; r < 4; ++r) {
                const int v = vt * 16 + 4 * quad + r;
                if (v < 25) {
                    const int oi = o * 100 + tl * 25 + v;
                    obuf[oi] = fmaxf(fmaf(obuf[oi], sc_l, acc[r] + aoff_l), 0.f);
                }
            }
        }
    }
    __syncthreads();

    // flush out tile via flat float4 (fully coalesced)
    for (int j = tid; j < 1600; j += 512) {
        const int o2 = j / 25, f4 = j - 25 * o2;
        *(float4*)(out + (size_t)(n * 64 + o2) * 7500 + t0q * 25 + f4 * 4) =
            *(const float4*)&obuf[o2 * 100 + f4 * 4];
    }
}

// ---------------------------------------------------------------------------
extern "C" void kernel_launch(void* const* d_in, const int* in_sizes, int n_in,
                              void* d_out, int out_size, void* d_ws, size_t ws_size,
                              hipStream_t stream)
{
    const float* x       = (const float*)d_in[0];
    const float* dbn_g   = (const float*)d_in[1];
    const float* dbn_b   = (const float*)d_in[2];
    const float* dbn_m   = (const float*)d_in[3];
    const float* dbn_v   = (const float*)d_in[4];
    const float* qkv_w   = (const float*)d_in[5];
    const float* qkv_b   = (const float*)d_in[6];
    const float* key_rel = (const float*)d_in[7];
    const float* attn_w  = (const float*)d_in[8];
    const float* attn_b  = (const float*)d_in[9];
    const float* bn_g    = (const float*)d_in[10];
    const float* bn_b    = (const float*)d_in[11];
    const float* bn_m    = (const float*)d_in[12];
    const float* bn_v    = (const float*)d_in[13];
    float* out = (float*)d_out;
    unsigned* W = (unsigned*)d_ws;

    k_pre<<<26, 256, 0, stream>>>(dbn_g, dbn_b, dbn_m, dbn_v, qkv_w, qkv_b,
                                  key_rel, attn_w, attn_b, bn_g, bn_b, bn_m,
                                  bn_v, W);
    k_qkv<<<dim3(19, 16), 1024, 0, stream>>>(x, W);
    k_attn<<<1600, 256, 0, stream>>>(W);
    k_out<<<dim3(19, 16, 4), 512, 0, stream>>>(x, W, out);
}

// Round 9
// 213.823 us; speedup vs baseline: 1.1171x; 1.0941x over previous
//
#include <hip/hip_runtime.h>
#include <hip/hip_bf16.h>
#include <cstddef>

// Problem constants
#define NN 16
#define CC 64
#define TT 300
#define VV 25
#define NHH 4
#define DKHH 16
#define BB (NN * VV)          // 400
#define EPS 1e-5f
#define LOG2E 1.4426950408889634f

// Workspace layout (u32 units)
#define WS_QK    0            // u32[400][64][300]  q|k bf16, paired along o (q pre-scaled 0.25*log2e)
#define WS_V     7680000      // u32[400][64][152]  v bf16, paired along t (t>=300 zero-filled)
#define WS_AH    11571200     // u32[400][304][32]  attnh bf16, paired along d (dp), t-major
#define WS_REL   15462400     // u32[41][64][4] key_rel frags (slot = mtile+1, slot0 = zeros)
#define WS_AWF   15472896     // u32[4][2][64][4] attn_w B-frags (pre-scaled by bn scale)
#define WS_AOFF  15474944     // f32[64] fused attn_b+bn offset
#define WS_SCO   15475008     // f32[64] bn scale (for skip path)
#define WS_WFRAG 15475072     // u32[12][2][64][4] qkv_w B-frags (q pre-scaled 0.25*log2e)
#define WS_QB2   15481216     // f32[192] qkv_b (q pre-scaled)
#define WS_SCSH  15481408     // float2[1600] data_bn (sc, sh) per (c, v)

typedef __attribute__((ext_vector_type(8))) short short8;
typedef __attribute__((ext_vector_type(4))) float float4v;

union U8 { short8 v; unsigned int w[4]; };

// f32x2 -> packed bf16x2 (RNE). HW op if available, else manual.
__device__ __forceinline__ unsigned int pk2(float a, float b) {
#if __has_builtin(__builtin_amdgcn_cvt_pk_bf16_f32)
    typedef __attribute__((ext_vector_type(2))) __bf16 bf2;
    union { bf2 v; unsigned u; } c;
    c.v = __builtin_amdgcn_cvt_pk_bf16_f32(a, b);
    return c.u;
#else
    union { float f; unsigned u; } x, y;
    x.f = a; y.f = b;
    unsigned ua = x.u + 0x7FFFu + ((x.u >> 16) & 1u);
    unsigned ub = y.u + 0x7FFFu + ((y.u >> 16) & 1u);
    return (ua >> 16) | (ub & 0xFFFF0000u);
#endif
}

__device__ __forceinline__ float ex2(float x) {
#if __has_builtin(__builtin_amdgcn_exp2f)
    return __builtin_amdgcn_exp2f(x);
#else
    return exp2f(x);
#endif
}

__device__ __forceinline__ float rcpf_(float x) {
#if __has_builtin(__builtin_amdgcn_rcpf)
    return __builtin_amdgcn_rcpf(x);
#else
    return 1.f / x;
#endif
}

// ---------------------------------------------------------------------------
// k_pre: constant tables.
// ---------------------------------------------------------------------------
__global__ __launch_bounds__(256) void k_pre(
    const float* __restrict__ dbn_g, const float* __restrict__ dbn_b,
    const float* __restrict__ dbn_m, const float* __restrict__ dbn_v,
    const float* __restrict__ qkv_w, const float* __restrict__ qkv_b,
    const float* __restrict__ key_rel,
    const float* __restrict__ attn_w, const float* __restrict__ attn_b,
    const float* __restrict__ bn_g, const float* __restrict__ bn_b,
    const float* __restrict__ bn_m, const float* __restrict__ bn_v,
    unsigned* __restrict__ W)
{
    const int jid = blockIdx.x * 256 + threadIdx.x;
    if (jid < 2624) {                      // relfrag: 41 slots x 64 lanes
        const int k = jid >> 6, lane = jid & 63, col = lane & 15, quad = lane >> 4;
        const int mt = k - 1, m = mt * 16 + col;
        const bool ok = (quad < 2) && (mt >= 0) && (m < 2 * TT - 1);
        unsigned w[4];
        #pragma unroll
        for (int j2 = 0; j2 < 4; ++j2) {
            const int c = quad * 8 + 2 * j2;
            const float v0 = ok ? key_rel[m * 16 + c] : 0.f;
            const float v1 = ok ? key_rel[m * 16 + c + 1] : 0.f;
            w[j2] = pk2(v0, v1);
        }
        *(uint4*)&W[WS_REL + k * 256 + lane * 4] = make_uint4(w[0], w[1], w[2], w[3]);
    } else if (jid < 3136) {               // awfrag: 4 otiles x 2 chalf x 64
        const int e = jid - 2624;
        const int ot = e >> 7, ch = (e >> 6) & 1, lane = e & 63;
        const int col = lane & 15, quad = lane >> 4;
        const int o = ot * 16 + col;
        const float sc = bn_g[o] * rsqrtf(bn_v[o] + EPS);
        unsigned w[4];
        #pragma unroll
        for (int j2 = 0; j2 < 4; ++j2) {
            const int c = ch * 32 + quad * 8 + 2 * j2;
            w[j2] = pk2(attn_w[o * 64 + c] * sc, attn_w[o * 64 + c + 1] * sc);
        }
        *(uint4*)&W[WS_AWF + (ot * 2 + ch) * 256 + lane * 4] = make_uint4(w[0], w[1], w[2], w[3]);
    } else if (jid < 3200) {               // aoff
        const int o = jid - 3136;
        const float sc = bn_g[o] * rsqrtf(bn_v[o] + EPS);
        ((float*)(W + WS_AOFF))[o] = attn_b[o] * sc + bn_b[o] - bn_m[o] * sc;
    } else if (jid < 3264) {               // scO
        const int o = jid - 3200;
        ((float*)(W + WS_SCO))[o] = bn_g[o] * rsqrtf(bn_v[o] + EPS);
    } else if (jid < 4800) {               // wfrag: 12 otiles x 2 chalf x 64
        const int e = jid - 3264;
        const int ot = e >> 7, ch = (e >> 6) & 1, lane = e & 63;
        const int col = lane & 15, quad = lane >> 4;
        const int o = ot * 16 + col;
        const float qs = (o < 64) ? 0.25f * LOG2E : 1.f;
        unsigned w[4];
        #pragma unroll
        for (int j2 = 0; j2 < 4; ++j2) {
            const int c = ch * 32 + quad * 8 + 2 * j2;
            w[j2] = pk2(qkv_w[o * 64 + c] * qs, qkv_w[o * 64 + c + 1] * qs);
        }
        *(uint4*)&W[WS_WFRAG + (ot * 2 + ch) * 256 + lane * 4] = make_uint4(w[0], w[1], w[2], w[3]);
    } else if (jid < 4992) {               // qb2
        const int o = jid - 4800;
        ((float*)(W + WS_QB2))[o] = qkv_b[o] * ((o < 64) ? 0.25f * LOG2E : 1.f);
    } else if (jid < 6592) {               // data_bn sc/sh per (c*25+v)
        const int e = jid - 4992;
        const float sc = dbn_g[e] * rsqrtf(dbn_v[e] + EPS);
        const float sh = dbn_b[e] - dbn_m[e] * sc;
        ((float2*)(W + WS_SCSH))[e] = make_float2(sc, sh);
    }
}

// ---------------------------------------------------------------------------
// k_qkv (MFMA): per (t-tile, n), 1024 thr (16 waves = 4 otg x 4 v-quarter).
// ---------------------------------------------------------------------------
__global__ __launch_bounds__(1024) void k_qkv(
        const float* __restrict__ x, unsigned* __restrict__ W)
{
    const int tt = blockIdx.x, n = blockIdx.y, t0 = tt * 16;
    const int tid = threadIdx.x;
    const unsigned* wfrag = W + WS_WFRAG;
    const float* qb2 = (const float*)(W + WS_QB2);
    unsigned* qk_p = W + WS_QK;
    unsigned* v_p  = W + WS_V;

    __shared__ unsigned afrag[25 * 516];   // 51.6 KB
    __shared__ float2 sls[1600];           // 12.8 KB data_bn (sc,sh) table

    for (int i = tid; i < 1600; i += 1024)
        sls[i] = ((const float2*)(W + WS_SCSH))[i];
    __syncthreads();

    // stage: 3200 jobs = 32 c-pairs x 100 float4 (contiguous flat = t*25+v)
    for (int i = tid; i < 3200; i += 1024) {
        const int f4 = i % 100, cp = i / 100;
        const int c0 = cp * 2;
        float4 xa = make_float4(0.f, 0.f, 0.f, 0.f);
        float4 xb = make_float4(0.f, 0.f, 0.f, 0.f);
        if (tt < 18 || f4 < 75) {          // tail tile: only 300 floats valid
            const float* p = x + (size_t)(n * 64 + c0) * 7500 + tt * 400 + f4 * 4;
            xa = *(const float4*)p;
            xb = *(const float4*)(p + 7500);
        }
        const int ch = cp >> 4, qd = (cp >> 2) & 3, j2 = cp & 3;
        const float ea[4] = {xa.x, xa.y, xa.z, xa.w};
        const float eb[4] = {xb.x, xb.y, xb.z, xb.w};
        #pragma unroll
        for (int e = 0; e < 4; ++e) {
            const int flat = f4 * 4 + e;
            const int tl = (flat * 5243) >> 17;     // flat / 25
            const int v  = flat - 25 * tl;
            const float2 s0 = sls[c0 * 25 + v];
            const float2 s1 = sls[c0 * 25 + 25 + v];
            const float a0 = fmaf(ea[e], s0.x, s0.y);
            const float a1 = fmaf(eb[e], s1.x, s1.y);
            afrag[v * 516 + (ch * 64 + qd * 16 + tl) * 4 + j2] = pk2(a0, a1);
        }
    }
    __syncthreads();

    const int wvv = tid >> 6, lane = tid & 63, col = lane & 15, quad = lane >> 4;
    const int otg = wvv >> 2, vq = wvv & 3;
    const int vlo = (vq == 0) ? 0 : (1 + 6 * vq);   // 0,7,13,19
    const int vhi = 7 + 6 * vq;                      // 7,13,19,25
    const float4v zero4 = {0.f, 0.f, 0.f, 0.f};
    const bool tvalid = (t0 + 4 * quad + 3 < TT);

    U8 bf[3][2]; float qb_l[3];
    #pragma unroll
    for (int i = 0; i < 3; ++i) {
        const int ot = 3 * otg + i;
        #pragma unroll
        for (int ch = 0; ch < 2; ++ch) {
            const uint4 u = *(const uint4*)&wfrag[(ot * 2 + ch) * 256 + lane * 4];
            bf[i][ch].w[0] = u.x; bf[i][ch].w[1] = u.y; bf[i][ch].w[2] = u.z; bf[i][ch].w[3] = u.w;
        }
        qb_l[i] = qb2[ot * 16 + col];
    }

    for (int v = vlo; v < vhi; ++v) {
        const int b = n * 25 + v;
        U8 a0, a1;
        { const uint4 u = *(const uint4*)&afrag[v * 516 + lane * 4];
          a0.w[0] = u.x; a0.w[1] = u.y; a0.w[2] = u.z; a0.w[3] = u.w; }
        { const uint4 u = *(const uint4*)&afrag[v * 516 + 256 + lane * 4];
          a1.w[0] = u.x; a1.w[1] = u.y; a1.w[2] = u.z; a1.w[3] = u.w; }
        #pragma unroll
        for (int i = 0; i < 3; ++i) {
            const int ot = 3 * otg + i;
            float4v acc = __builtin_amdgcn_mfma_f32_16x16x32_bf16(a0.v, bf[i][0].v, zero4, 0, 0, 0);
            acc = __builtin_amdgcn_mfma_f32_16x16x32_bf16(a1.v, bf[i][1].v, acc, 0, 0, 0);
            float val[4];
            #pragma unroll
            for (int r = 0; r < 4; ++r) val[r] = acc[r] + qb_l[i];
            if (ot < 8) {                  // q|k: pair neighbor o lanes
                unsigned pk[4];
                #pragma unroll
                for (int r = 0; r < 4; ++r) {
                    const float p = __shfl_xor(val[r], 1);
                    pk[r] = pk2(val[r], p);
                }
                if (((col & 1) == 0) && tvalid) {
                    const int op = ot * 8 + (col >> 1);
                    *(uint4*)&qk_p[(size_t)(b * 64 + op) * TT + t0 + 4 * quad] =
                        make_uint4(pk[0], pk[1], pk[2], pk[3]);
                }
            } else {                       // v: pair along t; zero-fill t>=300
                const int d = (ot - 8) * 16 + col;
                uint2 u;
                if (tvalid) { u.x = pk2(val[0], val[1]); u.y = pk2(val[2], val[3]); }
                else        { u.x = 0u; u.y = 0u; }
                *(uint2*)&v_p[(size_t)(b * 64 + d) * 152 + 8 * tt + 2 * quad] = u;
            }
        }
    }
}

// ---------------------------------------------------------------------------
// k_attn: ONE block per (b,h) (grid 1600, 4 waves), tiles strided by 4.
// kbuf/vbuf staged once. Aligned s-ring b128 reads on the QK critical path.
// Ring writes in mod-form (R6 measured-best). Unroll-3 chunk pipeline.
// Finalize pairs d via shfl and stores ah2[b][t][dp] (t-major, d-paired) so
// k_out's staging reads contiguous 128B runs.
// ---------------------------------------------------------------------------
__global__ __launch_bounds__(256, 4) void k_attn(unsigned* __restrict__ W)
{
    const int bh = blockIdx.x;             // 0..1599
    const int b = bh >> 2, h = bh & 3;
    const int tid  = threadIdx.x;
    const int wave = tid >> 6, lane = tid & 63;
    const int col  = lane & 15, quad = lane >> 4;

    const unsigned* qk_p = W + WS_QK;
    const unsigned* v_p  = W + WS_V;
    unsigned* ah_p = W + WS_AH;
    const unsigned* relfrag = W + WS_REL;

    __shared__ unsigned kbuf[19 * 32 * 4];   // 9.7 KB
    __shared__ unsigned vbuf[10 * 64 * 4];   // 10.2 KB (s-permuted)
    __shared__ float relbuf[4][16 * 68];     // per-wave s-ring (64 slots + pad)

    for (int p = tid; p < 2432; p += 256) {
        const int c = p & 15, j2 = (p >> 4) & 3, qh = (p >> 6) & 1, st = p >> 7;
        kbuf[(st * 32 + qh * 16 + c) * 4 + j2] =
            qk_p[(size_t)(b * 64 + 32 + h * 8 + qh * 4 + j2) * TT + st * 16 + c];
    }
    // V staging with k<->s permutation: quad q of the PV A/B frag owns
    // s-pairs {2q, 2q+1, 8+2q, 8+2q+1} within each 32-s chunk.
    for (int p = tid; p < 640; p += 256) {
        const int tq = p % 40, d = p / 40;
        const int off = (tq * 4 <= 148) ? tq * 4 : 144;  // clamp (slots unused)
        const uint4 u = *(const uint4*)&v_p[(size_t)(b * 64 + h * 16 + d) * 152 + off];
        const int c = tq >> 2;
        const int l0 = (tq & 3) * 4;
        const unsigned uu[4] = {u.x, u.y, u.z, u.w};
        #pragma unroll
        for (int j = 0; j < 4; ++j) {
            const int local = l0 + j;
            const int q  = (local < 8) ? (local >> 1) : ((local - 8) >> 1);
            const int j2 = (local < 8) ? (local & 1) : (2 + (local & 1));
            vbuf[(c * 64 + q * 16 + d) * 4 + j2] = uu[j];
        }
    }
    __syncthreads();

    float* relw = &relbuf[wave][0];
    const float4v zero4 = {0.f, 0.f, 0.f, 0.f};
    U8 onef;
    onef.w[0] = onef.w[1] = onef.w[2] = onef.w[3] = 0x3F803F80u;

    for (int tt = wave; tt < 19; tt += 4) {
        const int t0 = tt * 16;

        // ---- Q B-frag (cols = t) ----
        U8 qf;
        if (quad < 2) {
            int t = t0 + col; if (t > TT - 1) t = TT - 1;
            const size_t rb = (size_t)(b * 64 + h * 8 + quad * 4) * TT + t;
            qf.w[0] = qk_p[rb];
            qf.w[1] = qk_p[rb + TT];
            qf.w[2] = qk_p[rb + 2 * TT];
            qf.w[3] = qk_p[rb + 3 * TT];
        } else {
            qf.w[0] = qf.w[1] = qf.w[2] = qf.w[3] = 0u;
        }

        auto rel_ld = [&](int mt) -> uint4 {
            return *(const uint4*)&relfrag[(mt + 1) * 256 + lane * 4];
        };
        // s-ring write: slot(s) = (m + t - 299) mod 64, s = diag index.
        // lane holds R[m = mt*16+4q+r, t = t0+col]; -299 == +21 (mod 64).
        auto rel_do = [&](int mt, uint4 u) {
            U8 kr; kr.w[0] = u.x; kr.w[1] = u.y; kr.w[2] = u.z; kr.w[3] = u.w;
            const float4v rc = __builtin_amdgcn_mfma_f32_16x16x32_bf16(
                                   kr.v, qf.v, zero4, 0, 0, 0);
            const int wbase = mt * 16 + 4 * quad + t0 + col + 21;
            float* rw = &relw[col * 68];
            rw[wbase & 63]       = rc[0];
            rw[(wbase + 1) & 63] = rc[1];
            rw[(wbase + 2) & 63] = rc[2];
            rw[(wbase + 3) & 63] = rc[3];
        };

        #pragma unroll
        for (int i = 0; i < 4; ++i) rel_do(17 - tt + i, rel_ld(17 - tt + i));
        uint4 ru0 = rel_ld(21 - tt), ru1 = rel_ld(22 - tt);

        float4v accPV = zero4;
        float4v accS  = zero4;

        #pragma unroll 3
        for (int c = 0; c < 9; ++c) {       // chunks of 2 s-tiles: s 0..287
            U8 kf0, kf1;
            if (quad < 2) {
                const uint4 u0 = *(const uint4*)&kbuf[((2 * c) * 32 + quad * 16 + col) * 4];
                const uint4 u1 = *(const uint4*)&kbuf[((2 * c + 1) * 32 + quad * 16 + col) * 4];
                kf0.w[0] = u0.x; kf0.w[1] = u0.y; kf0.w[2] = u0.z; kf0.w[3] = u0.w;
                kf1.w[0] = u1.x; kf1.w[1] = u1.y; kf1.w[2] = u1.z; kf1.w[3] = u1.w;
            } else {
                kf0.w[0] = kf0.w[1] = kf0.w[2] = kf0.w[3] = 0u;
                kf1.w[0] = kf1.w[1] = kf1.w[2] = kf1.w[3] = 0u;
            }
            const short8 vf = *(const short8*)&vbuf[(c * 64 + lane) * 4];

            // aligned s-ring reads: rows s = 32c+4q+r (qk0), +16 (qk1)
            const int rb0 = (32 * c + 4 * quad) & 63;
            const float4v rc0 = *(const float4v*)&relw[col * 68 + rb0];
            const float4v rc1 = *(const float4v*)&relw[col * 68 + ((rb0 + 16) & 63)];
            const float4v qk0 = __builtin_amdgcn_mfma_f32_16x16x32_bf16(kf0.v, qf.v, rc0, 0, 0, 0);
            const float4v qk1 = __builtin_amdgcn_mfma_f32_16x16x32_bf16(kf1.v, qf.v, rc1, 0, 0, 0);

            const float e0 = ex2(qk0[0]);
            const float e1 = ex2(qk0[1]);
            const float e2 = ex2(qk0[2]);
            const float e3 = ex2(qk0[3]);
            const float e4 = ex2(qk1[0]);
            const float e5 = ex2(qk1[1]);
            const float e6 = ex2(qk1[2]);
            const float e7 = ex2(qk1[3]);

            U8 pf;
            pf.w[0] = pk2(e0, e1);
            pf.w[1] = pk2(e2, e3);
            pf.w[2] = pk2(e4, e5);
            pf.w[3] = pk2(e6, e7);
            accPV = __builtin_amdgcn_mfma_f32_16x16x32_bf16(pf.v, vf, accPV, 0, 0, 0);
            accS  = __builtin_amdgcn_mfma_f32_16x16x32_bf16(pf.v, onef.v, accS, 0, 0, 0);

            rel_do(2 * c + 21 - tt, ru0);
            rel_do(2 * c + 22 - tt, ru1);
            if (c < 8) { ru0 = rel_ld(2 * c + 23 - tt); ru1 = rel_ld(2 * c + 24 - tt); }
        }

        // ---- tail chunk 9: stile 18 only (s 288..303; s>=300 masked) ----
        {
            U8 kf0;
            if (quad < 2) {
                const uint4 u0 = *(const uint4*)&kbuf[(18 * 32 + quad * 16 + col) * 4];
                kf0.w[0] = u0.x; kf0.w[1] = u0.y; kf0.w[2] = u0.z; kf0.w[3] = u0.w;
            } else {
                kf0.w[0] = kf0.w[1] = kf0.w[2] = kf0.w[3] = 0u;
            }
            const int rb0 = (288 + 4 * quad) & 63;
            const float4v rc0 = *(const float4v*)&relw[col * 68 + rb0];
            const float4v qk0 = __builtin_amdgcn_mfma_f32_16x16x32_bf16(kf0.v, qf.v, rc0, 0, 0, 0);
            float e0 = ex2(qk0[0]);
            float e1 = ex2(qk0[1]);
            float e2 = ex2(qk0[2]);
            float e3 = ex2(qk0[3]);
            if (quad == 3) { e0 = e1 = e2 = e3 = 0.f; }
            U8 pf;
            pf.w[0] = pk2(e0, e1);
            pf.w[1] = pk2(e2, e3);
            pf.w[2] = 0u;
            pf.w[3] = 0u;
            const short8 vf = *(const short8*)&vbuf[(9 * 64 + lane) * 4];
            accPV = __builtin_amdgcn_mfma_f32_16x16x32_bf16(pf.v, vf, accPV, 0, 0, 0);
            accS  = __builtin_amdgcn_mfma_f32_16x16x32_bf16(pf.v, onef.v, accS, 0, 0, 0);
        }

        // ---- finalize: normalize, pair along d via shfl, store to
        // ah2[b][t][dp] (t-major). Even-col lanes write 4 u32 (t = t0+4q+r).
        // t >= 300 lands in the t<304 pad (never read by k_out). ----
        {
            float val[4];
            #pragma unroll
            for (int r = 0; r < 4; ++r) val[r] = accPV[r] * rcpf_(accS[r]);
            unsigned w[4];
            #pragma unroll
            for (int r = 0; r < 4; ++r) {
                const float p = __shfl_xor(val[r], 1);
                w[r] = pk2(val[r], p);
            }
            if ((col & 1) == 0) {
                const int dp = h * 8 + (col >> 1);
                unsigned* dst = ah_p + (size_t)(b * 304 + t0 + 4 * quad) * 32 + dp;
                #pragma unroll
                for (int r = 0; r < 4; ++r) dst[r * 32] = w[r];
            }
        }
    }
}

// ---------------------------------------------------------------------------
// k_out (MFMA): per (t-tile, n, t-quarter), 512 thr (waves = otile x t-half).
// ah staged from d-paired t-major ah2 via coalesced uint4 loads (128B runs
// per (b,t)) and uint4 LDS writes into the A-frag layout.
// ---------------------------------------------------------------------------
__global__ __launch_bounds__(512) void k_out(
        const float* __restrict__ x, const unsigned* __restrict__ W,
        float* __restrict__ out)
{
    const int tt = blockIdx.x, n = blockIdx.y, tq = blockIdx.z;
    if (tt == 18 && tq == 3) return;
    const int t0q = tt * 16 + tq * 4;
    const int tid = threadIdx.x;
    const unsigned* ah_p = W + WS_AH;
    const unsigned* awfrag = W + WS_AWF;
    const float* aoff = (const float*)(W + WS_AOFF);
    const float* scO  = (const float*)(W + WS_SCO);

    __shared__ unsigned fbuf[4 * 1024];    // 16 KB (ah A-frags)
    __shared__ float obuf[6400];           // 25.6 KB (x tile, then out tile)

    // stage x tile (64 o x 4 t x 25 v) via flat float4 (fully coalesced)
    for (int j = tid; j < 1600; j += 512) {
        const int o = j / 25, f4 = j - 25 * o;
        const float4 xv = *(const float4*)(x + (size_t)(n * 64 + o) * 7500 + t0q * 25 + f4 * 4);
        *(float4*)&obuf[o * 100 + f4 * 4] = xv;
    }
    // stage ah A-frags: 800 uint4 jobs = 25 v x 4 tl x 8 dp4.
    // Each uint4 = 4 consecutive dp words (pc = 4*dp4 + j2, j2 = 0..3) ->
    // 4 consecutive fbuf slots (ch = dp4>>2, qd = dp4&3, j2 runs 0..3).
    for (int i = tid; i < 800; i += 512) {
        const int dp4 = i & 7, g = i >> 3;
        const int tl = g & 3, v = g >> 2;
        const int b = n * 25 + v;
        const uint4 u = *(const uint4*)&ah_p[(size_t)(b * 304 + t0q + tl) * 32 + dp4 * 4];
        const int vt = v >> 4, cv = v & 15, ch = dp4 >> 2, qd = dp4 & 3;
        const int xi0 = (vt * 2 + ch) * 256 + (qd * 16 + (cv ^ qd)) * 4;
        *(uint4*)&fbuf[tl * 1024 + ((xi0 + 12 * tl) & 1023)] = u;
    }
    __syncthreads();

    const int wv = tid >> 6, lane = tid & 63, col = lane & 15, quad = lane >> 4;
    const int ow = wv & 3, th = wv >> 2;
    const int o = ow * 16 + col;
    const float4v zero4 = {0.f, 0.f, 0.f, 0.f};

    U8 awf0, awf1;
    { const uint4 u = *(const uint4*)&awfrag[(ow * 2 + 0) * 256 + lane * 4];
      awf0.w[0] = u.x; awf0.w[1] = u.y; awf0.w[2] = u.z; awf0.w[3] = u.w; }
    { const uint4 u = *(const uint4*)&awfrag[(ow * 2 + 1) * 256 + lane * 4];
      awf1.w[0] = u.x; awf1.w[1] = u.y; awf1.w[2] = u.z; awf1.w[3] = u.w; }
    const float aoff_l = aoff[o], sc_l = scO[o];

    for (int tl = 2 * th; tl < 2 * th + 2; ++tl) {
        #pragma unroll
        for (int vt = 0; vt < 2; ++vt) {
            U8 a0, a1;
            { const int xb = (vt * 2 + 0) * 256 + (quad * 16 + (col ^ quad)) * 4;
              const uint4 u = *(const uint4*)&fbuf[tl * 1024 + ((xb + 12 * tl) & 1023)];
              a0.w[0] = u.x; a0.w[1] = u.y; a0.w[2] = u.z; a0.w[3] = u.w; }
            { const int xb = (vt * 2 + 1) * 256 + (quad * 16 + (col ^ quad)) * 4;
              const uint4 u = *(const uint4*)&fbuf[tl * 1024 + ((xb + 12 * tl) & 1023)];
              a1.w[0] = u.x; a1.w[1] = u.y; a1.w[2] = u.z; a1.w[3] = u.w; }
            float4v acc = __builtin_amdgcn_mfma_f32_16x16x32_bf16(a0.v, awf0.v, zero4, 0, 0, 0);
            acc = __builtin_amdgcn_mfma_f32_16x16x32_bf16(a1.v, awf1.v, acc, 0, 0, 0);
            #pragma unroll
            for (int r = 0; r < 4; ++r) {
                const int v = vt * 16 + 4 * quad + r;
                if (v < 25) {
                    const int oi = o * 100 + tl * 25 + v;
                    obuf[oi] = fmaxf(fmaf(obuf[oi], sc_l, acc[r] + aoff_l), 0.f);
                }
            }
        }
    }
    __syncthreads();

    // flush out tile via flat float4 (fully coalesced)
    for (int j = tid; j < 1600; j += 512) {
        const int o2 = j / 25, f4 = j - 25 * o2;
        *(float4*)(out + (size_t)(n * 64 + o2) * 7500 + t0q * 25 + f4 * 4) =
            *(const float4*)&obuf[o2 * 100 + f4 * 4];
    }
}

// ---------------------------------------------------------------------------
extern "C" void kernel_launch(void* const* d_in, const int* in_sizes, int n_in,
                              void* d_out, int out_size, void* d_ws, size_t ws_size,
                              hipStream_t stream)
{
    const float* x       = (const float*)d_in[0];
    const float* dbn_g   = (const float*)d_in[1];
    const float* dbn_b   = (const float*)d_in[2];
    const float* dbn_m   = (const float*)d_in[3];
    const float* dbn_v   = (const float*)d_in[4];
    const float* qkv_w   = (const float*)d_in[5];
    const float* qkv_b   = (const float*)d_in[6];
    const float* key_rel = (const float*)d_in[7];
    const float* attn_w  = (const float*)d_in[8];
    const float* attn_b  = (const float*)d_in[9];
    const float* bn_g    = (const float*)d_in[10];
    const float* bn_b    = (const float*)d_in[11];
    const float* bn_m    = (const float*)d_in[12];
    const float* bn_v    = (const float*)d_in[13];
    float* out = (float*)d_out;
    unsigned* W = (unsigned*)d_ws;

    k_pre<<<26, 256, 0, stream>>>(dbn_g, dbn_b, dbn_m, dbn_v, qkv_w, qkv_b,
                                  key_rel, attn_w, attn_b, bn_g, bn_b, bn_m,
                                  bn_v, W);
    k_qkv<<<dim3(19, 16), 1024, 0, stream>>>(x, W);
    k_attn<<<1600, 256, 0, stream>>>(W);
    k_out<<<dim3(19, 16, 4), 512, 0, stream>>>(x, W, out);
}

// Round 10
// 201.590 us; speedup vs baseline: 1.1848x; 1.0607x over previous
//
#include <hip/hip_runtime.h>
#include <hip/hip_bf16.h>
#include <cstddef>

// Problem constants
#define NN 16
#define CC 64
#define TT 300
#define VV 25
#define NHH 4
#define DKHH 16
#define BB (NN * VV)          // 400
#define EPS 1e-5f
#define LOG2E 1.4426950408889634f

// Workspace layout (u32 units)
#define WS_QK    0            // u32[400][64][300]  q|k bf16, paired along o (q pre-scaled 0.25*log2e)
#define WS_V     7680000      // u32[400][64][152]  v bf16, paired along t (t>=300 zero-filled)
#define WS_AH    11571200     // u32[400][304][32]  attnh bf16, paired along d (dp), t-major
#define WS_REL   15462400     // u32[41][64][4] key_rel frags (slot = mtile+1, slot0 = zeros)
#define WS_AWF   15472896     // u32[4][2][64][4] attn_w B-frags (pre-scaled by bn scale)
#define WS_AOFF  15474944     // f32[64] fused attn_b+bn offset
#define WS_SCO   15475008     // f32[64] bn scale (for skip path)
#define WS_WFRAG 15475072     // u32[12][2][64][4] qkv_w B-frags (q pre-scaled 0.25*log2e)
#define WS_QB2   15481216     // f32[192] qkv_b (q pre-scaled)
#define WS_SCSH  15481408     // float2[1600] data_bn (sc, sh) per (c, v)

typedef __attribute__((ext_vector_type(8))) short short8;
typedef __attribute__((ext_vector_type(4))) float float4v;

union U8 { short8 v; unsigned int w[4]; };

// f32x2 -> packed bf16x2 (RNE). HW op if available, else manual.
__device__ __forceinline__ unsigned int pk2(float a, float b) {
#if __has_builtin(__builtin_amdgcn_cvt_pk_bf16_f32)
    typedef __attribute__((ext_vector_type(2))) __bf16 bf2;
    union { bf2 v; unsigned u; } c;
    c.v = __builtin_amdgcn_cvt_pk_bf16_f32(a, b);
    return c.u;
#else
    union { float f; unsigned u; } x, y;
    x.f = a; y.f = b;
    unsigned ua = x.u + 0x7FFFu + ((x.u >> 16) & 1u);
    unsigned ub = y.u + 0x7FFFu + ((y.u >> 16) & 1u);
    return (ua >> 16) | (ub & 0xFFFF0000u);
#endif
}

__device__ __forceinline__ float ex2(float x) {
#if __has_builtin(__builtin_amdgcn_exp2f)
    return __builtin_amdgcn_exp2f(x);
#else
    return exp2f(x);
#endif
}

__device__ __forceinline__ float rcpf_(float x) {
#if __has_builtin(__builtin_amdgcn_rcpf)
    return __builtin_amdgcn_rcpf(x);
#else
    return 1.f / x;
#endif
}

// ---------------------------------------------------------------------------
// k_pre: constant tables.
// ---------------------------------------------------------------------------
__global__ __launch_bounds__(256) void k_pre(
    const float* __restrict__ dbn_g, const float* __restrict__ dbn_b,
    const float* __restrict__ dbn_m, const float* __restrict__ dbn_v,
    const float* __restrict__ qkv_w, const float* __restrict__ qkv_b,
    const float* __restrict__ key_rel,
    const float* __restrict__ attn_w, const float* __restrict__ attn_b,
    const float* __restrict__ bn_g, const float* __restrict__ bn_b,
    const float* __restrict__ bn_m, const float* __restrict__ bn_v,
    unsigned* __restrict__ W)
{
    const int jid = blockIdx.x * 256 + threadIdx.x;
    if (jid < 2624) {                      // relfrag: 41 slots x 64 lanes
        const int k = jid >> 6, lane = jid & 63, col = lane & 15, quad = lane >> 4;
        const int mt = k - 1, m = mt * 16 + col;
        const bool ok = (quad < 2) && (mt >= 0) && (m < 2 * TT - 1);
        unsigned w[4];
        #pragma unroll
        for (int j2 = 0; j2 < 4; ++j2) {
            const int c = quad * 8 + 2 * j2;
            const float v0 = ok ? key_rel[m * 16 + c] : 0.f;
            const float v1 = ok ? key_rel[m * 16 + c + 1] : 0.f;
            w[j2] = pk2(v0, v1);
        }
        *(uint4*)&W[WS_REL + k * 256 + lane * 4] = make_uint4(w[0], w[1], w[2], w[3]);
    } else if (jid < 3136) {               // awfrag: 4 otiles x 2 chalf x 64
        const int e = jid - 2624;
        const int ot = e >> 7, ch = (e >> 6) & 1, lane = e & 63;
        const int col = lane & 15, quad = lane >> 4;
        const int o = ot * 16 + col;
        const float sc = bn_g[o] * rsqrtf(bn_v[o] + EPS);
        unsigned w[4];
        #pragma unroll
        for (int j2 = 0; j2 < 4; ++j2) {
            const int c = ch * 32 + quad * 8 + 2 * j2;
            w[j2] = pk2(attn_w[o * 64 + c] * sc, attn_w[o * 64 + c + 1] * sc);
        }
        *(uint4*)&W[WS_AWF + (ot * 2 + ch) * 256 + lane * 4] = make_uint4(w[0], w[1], w[2], w[3]);
    } else if (jid < 3200) {               // aoff
        const int o = jid - 3136;
        const float sc = bn_g[o] * rsqrtf(bn_v[o] + EPS);
        ((float*)(W + WS_AOFF))[o] = attn_b[o] * sc + bn_b[o] - bn_m[o] * sc;
    } else if (jid < 3264) {               // scO
        const int o = jid - 3200;
        ((float*)(W + WS_SCO))[o] = bn_g[o] * rsqrtf(bn_v[o] + EPS);
    } else if (jid < 4800) {               // wfrag: 12 otiles x 2 chalf x 64
        const int e = jid - 3264;
        const int ot = e >> 7, ch = (e >> 6) & 1, lane = e & 63;
        const int col = lane & 15, quad = lane >> 4;
        const int o = ot * 16 + col;
        const float qs = (o < 64) ? 0.25f * LOG2E : 1.f;
        unsigned w[4];
        #pragma unroll
        for (int j2 = 0; j2 < 4; ++j2) {
            const int c = ch * 32 + quad * 8 + 2 * j2;
            w[j2] = pk2(qkv_w[o * 64 + c] * qs, qkv_w[o * 64 + c + 1] * qs);
        }
        *(uint4*)&W[WS_WFRAG + (ot * 2 + ch) * 256 + lane * 4] = make_uint4(w[0], w[1], w[2], w[3]);
    } else if (jid < 4992) {               // qb2
        const int o = jid - 4800;
        ((float*)(W + WS_QB2))[o] = qkv_b[o] * ((o < 64) ? 0.25f * LOG2E : 1.f);
    } else if (jid < 6592) {               // data_bn sc/sh per (c*25+v)
        const int e = jid - 4992;
        const float sc = dbn_g[e] * rsqrtf(dbn_v[e] + EPS);
        const float sh = dbn_b[e] - dbn_m[e] * sc;
        ((float2*)(W + WS_SCSH))[e] = make_float2(sc, sh);
    }
}

// ---------------------------------------------------------------------------
// k_qkv (MFMA): per (t-tile, n), 1024 thr (16 waves = 4 otg x 4 v-quarter).
// ---------------------------------------------------------------------------
__global__ __launch_bounds__(1024) void k_qkv(
        const float* __restrict__ x, unsigned* __restrict__ W)
{
    const int tt = blockIdx.x, n = blockIdx.y, t0 = tt * 16;
    const int tid = threadIdx.x;
    const unsigned* wfrag = W + WS_WFRAG;
    const float* qb2 = (const float*)(W + WS_QB2);
    unsigned* qk_p = W + WS_QK;
    unsigned* v_p  = W + WS_V;

    __shared__ unsigned afrag[25 * 516];   // 51.6 KB
    __shared__ float2 sls[1600];           // 12.8 KB data_bn (sc,sh) table

    for (int i = tid; i < 1600; i += 1024)
        sls[i] = ((const float2*)(W + WS_SCSH))[i];
    __syncthreads();

    // stage: 3200 jobs = 32 c-pairs x 100 float4 (contiguous flat = t*25+v)
    for (int i = tid; i < 3200; i += 1024) {
        const int f4 = i % 100, cp = i / 100;
        const int c0 = cp * 2;
        float4 xa = make_float4(0.f, 0.f, 0.f, 0.f);
        float4 xb = make_float4(0.f, 0.f, 0.f, 0.f);
        if (tt < 18 || f4 < 75) {          // tail tile: only 300 floats valid
            const float* p = x + (size_t)(n * 64 + c0) * 7500 + tt * 400 + f4 * 4;
            xa = *(const float4*)p;
            xb = *(const float4*)(p + 7500);
        }
        const int ch = cp >> 4, qd = (cp >> 2) & 3, j2 = cp & 3;
        const float ea[4] = {xa.x, xa.y, xa.z, xa.w};
        const float eb[4] = {xb.x, xb.y, xb.z, xb.w};
        #pragma unroll
        for (int e = 0; e < 4; ++e) {
            const int flat = f4 * 4 + e;
            const int tl = (flat * 5243) >> 17;     // flat / 25
            const int v  = flat - 25 * tl;
            const float2 s0 = sls[c0 * 25 + v];
            const float2 s1 = sls[c0 * 25 + 25 + v];
            const float a0 = fmaf(ea[e], s0.x, s0.y);
            const float a1 = fmaf(eb[e], s1.x, s1.y);
            afrag[v * 516 + (ch * 64 + qd * 16 + tl) * 4 + j2] = pk2(a0, a1);
        }
    }
    __syncthreads();

    const int wvv = tid >> 6, lane = tid & 63, col = lane & 15, quad = lane >> 4;
    const int otg = wvv >> 2, vq = wvv & 3;
    const int vlo = (vq == 0) ? 0 : (1 + 6 * vq);   // 0,7,13,19
    const int vhi = 7 + 6 * vq;                      // 7,13,19,25
    const float4v zero4 = {0.f, 0.f, 0.f, 0.f};
    const bool tvalid = (t0 + 4 * quad + 3 < TT);

    U8 bf[3][2]; float qb_l[3];
    #pragma unroll
    for (int i = 0; i < 3; ++i) {
        const int ot = 3 * otg + i;
        #pragma unroll
        for (int ch = 0; ch < 2; ++ch) {
            const uint4 u = *(const uint4*)&wfrag[(ot * 2 + ch) * 256 + lane * 4];
            bf[i][ch].w[0] = u.x; bf[i][ch].w[1] = u.y; bf[i][ch].w[2] = u.z; bf[i][ch].w[3] = u.w;
        }
        qb_l[i] = qb2[ot * 16 + col];
    }

    for (int v = vlo; v < vhi; ++v) {
        const int b = n * 25 + v;
        U8 a0, a1;
        { const uint4 u = *(const uint4*)&afrag[v * 516 + lane * 4];
          a0.w[0] = u.x; a0.w[1] = u.y; a0.w[2] = u.z; a0.w[3] = u.w; }
        { const uint4 u = *(const uint4*)&afrag[v * 516 + 256 + lane * 4];
          a1.w[0] = u.x; a1.w[1] = u.y; a1.w[2] = u.z; a1.w[3] = u.w; }
        #pragma unroll
        for (int i = 0; i < 3; ++i) {
            const int ot = 3 * otg + i;
            float4v acc = __builtin_amdgcn_mfma_f32_16x16x32_bf16(a0.v, bf[i][0].v, zero4, 0, 0, 0);
            acc = __builtin_amdgcn_mfma_f32_16x16x32_bf16(a1.v, bf[i][1].v, acc, 0, 0, 0);
            float val[4];
            #pragma unroll
            for (int r = 0; r < 4; ++r) val[r] = acc[r] + qb_l[i];
            if (ot < 8) {                  // q|k: pair neighbor o lanes
                unsigned pk[4];
                #pragma unroll
                for (int r = 0; r < 4; ++r) {
                    const float p = __shfl_xor(val[r], 1);
                    pk[r] = pk2(val[r], p);
                }
                if (((col & 1) == 0) && tvalid) {
                    const int op = ot * 8 + (col >> 1);
                    *(uint4*)&qk_p[(size_t)(b * 64 + op) * TT + t0 + 4 * quad] =
                        make_uint4(pk[0], pk[1], pk[2], pk[3]);
                }
            } else {                       // v: pair along t; zero-fill t>=300
                const int d = (ot - 8) * 16 + col;
                uint2 u;
                if (tvalid) { u.x = pk2(val[0], val[1]); u.y = pk2(val[2], val[3]); }
                else        { u.x = 0u; u.y = 0u; }
                *(uint2*)&v_p[(size_t)(b * 64 + d) * 152 + 8 * tt + 2 * quad] = u;
            }
        }
    }
}

// ---------------------------------------------------------------------------
// k_attn: ONE block per (b,h) (grid 1600, 4 waves), tiles strided by 4.
// Fully-unrolled 9-chunk loop with PRECOMPUTED parity-alternating ring
// addresses: slot step per chunk is +32 mod 64 = ^32, and the write-slot
// base (357+4q+col) is tt-invariant, so all ring offsets are loop-invariant
// registers and kbuf/vbuf reads use compile-time immediate offsets. Same
// memory pattern as R6 (conflicts/absmax identical) with the per-chunk
// address VALU removed.
// ---------------------------------------------------------------------------
__global__ __launch_bounds__(256, 4) void k_attn(unsigned* __restrict__ W)
{
    const int bh = blockIdx.x;             // 0..1599
    const int b = bh >> 2, h = bh & 3;
    const int tid  = threadIdx.x;
    const int wave = tid >> 6, lane = tid & 63;
    const int col  = lane & 15, quad = lane >> 4;

    const unsigned* qk_p = W + WS_QK;
    const unsigned* v_p  = W + WS_V;
    unsigned* ah_p = W + WS_AH;
    const unsigned* relfrag = W + WS_REL;

    __shared__ unsigned kbuf[19 * 32 * 4];   // 9.7 KB
    __shared__ unsigned vbuf[10 * 64 * 4];   // 10.2 KB (s-permuted)
    __shared__ float relbuf[4][16 * 68];     // per-wave s-ring (64 slots + pad)

    for (int p = tid; p < 2432; p += 256) {
        const int c = p & 15, j2 = (p >> 4) & 3, qh = (p >> 6) & 1, st = p >> 7;
        kbuf[(st * 32 + qh * 16 + c) * 4 + j2] =
            qk_p[(size_t)(b * 64 + 32 + h * 8 + qh * 4 + j2) * TT + st * 16 + c];
    }
    // V staging with k<->s permutation: quad q of the PV A/B frag owns
    // s-pairs {2q, 2q+1, 8+2q, 8+2q+1} within each 32-s chunk.
    for (int p = tid; p < 640; p += 256) {
        const int tq = p % 40, d = p / 40;
        const int off = (tq * 4 <= 148) ? tq * 4 : 144;  // clamp (slots unused)
        const uint4 u = *(const uint4*)&v_p[(size_t)(b * 64 + h * 16 + d) * 152 + off];
        const int c = tq >> 2;
        const int l0 = (tq & 3) * 4;
        const unsigned uu[4] = {u.x, u.y, u.z, u.w};
        #pragma unroll
        for (int j = 0; j < 4; ++j) {
            const int local = l0 + j;
            const int q  = (local < 8) ? (local >> 1) : ((local - 8) >> 1);
            const int j2 = (local < 8) ? (local & 1) : (2 + (local & 1));
            vbuf[(c * 64 + q * 16 + d) * 4 + j2] = uu[j];
        }
    }
    __syncthreads();

    float* relw = &relbuf[wave][0];
    const float4v zero4 = {0.f, 0.f, 0.f, 0.f};
    U8 onef;
    onef.w[0] = onef.w[1] = onef.w[2] = onef.w[3] = 0x3F803F80u;

    // Loop-invariant ring offsets.
    // Writes: chunk c, rel_do #0 (mt=2c+21-tt) -> slot (357+4q+col+j) & 63,
    //         XOR 32 for odd c (tt-invariant: t0 cancels 16*tt).
    //         rel_do #1 (mt=2c+22-tt) -> +16.
    int sw[2][2][4];
    #pragma unroll
    for (int j = 0; j < 4; ++j) {
        const int a  = (357 + 4 * quad + col + j) & 63;
        const int b2 = (373 + 4 * quad + col + j) & 63;
        sw[0][0][j] = col * 68 + a;
        sw[0][1][j] = col * 68 + b2;
        sw[1][0][j] = col * 68 + (a ^ 32);
        sw[1][1][j] = col * 68 + (b2 ^ 32);
    }
    // Reads: chunk c -> slots (32c+4q)&63 = 4q ^ 32(c&1); +16 for rc1.
    const int ra0 = col * 68 + 4 * quad;
    const int ra1 = col * 68 + 4 * quad + 16;
    const int rb0x = col * 68 + (4 * quad ^ 32);
    const int rb1x = col * 68 + ((4 * quad + 16) ^ 32);

    for (int tt = wave; tt < 19; tt += 4) {
        const int t0 = tt * 16;

        // ---- Q B-frag (cols = t) ----
        U8 qf;
        if (quad < 2) {
            int t = t0 + col; if (t > TT - 1) t = TT - 1;
            const size_t rb = (size_t)(b * 64 + h * 8 + quad * 4) * TT + t;
            qf.w[0] = qk_p[rb];
            qf.w[1] = qk_p[rb + TT];
            qf.w[2] = qk_p[rb + 2 * TT];
            qf.w[3] = qk_p[rb + 3 * TT];
        } else {
            qf.w[0] = qf.w[1] = qf.w[2] = qf.w[3] = 0u;
        }

        auto rel_ld = [&](int mt) -> uint4 {
            return *(const uint4*)&relfrag[(mt + 1) * 256 + lane * 4];
        };
        // generic (mod-form) rel_do for the prologue only (4 calls/tile)
        auto rel_do = [&](int mt, uint4 u) {
            U8 kr; kr.w[0] = u.x; kr.w[1] = u.y; kr.w[2] = u.z; kr.w[3] = u.w;
            const float4v rc = __builtin_amdgcn_mfma_f32_16x16x32_bf16(
                                   kr.v, qf.v, zero4, 0, 0, 0);
            const int wbase = mt * 16 + 4 * quad + t0 + col + 21;
            float* rw = &relw[col * 68];
            rw[wbase & 63]       = rc[0];
            rw[(wbase + 1) & 63] = rc[1];
            rw[(wbase + 2) & 63] = rc[2];
            rw[(wbase + 3) & 63] = rc[3];
        };

        #pragma unroll
        for (int i = 0; i < 4; ++i) rel_do(17 - tt + i, rel_ld(17 - tt + i));
        uint4 ru0 = rel_ld(21 - tt), ru1 = rel_ld(22 - tt);

        float4v accPV = zero4;
        float4v accS  = zero4;

#define CHUNK(c, par) { \
    U8 kf0, kf1; \
    if (quad < 2) { \
        const uint4 u0 = *(const uint4*)&kbuf[((2 * (c)) * 32 + quad * 16 + col) * 4]; \
        const uint4 u1 = *(const uint4*)&kbuf[((2 * (c) + 1) * 32 + quad * 16 + col) * 4]; \
        kf0.w[0] = u0.x; kf0.w[1] = u0.y; kf0.w[2] = u0.z; kf0.w[3] = u0.w; \
        kf1.w[0] = u1.x; kf1.w[1] = u1.y; kf1.w[2] = u1.z; kf1.w[3] = u1.w; \
    } else { \
        kf0.w[0] = kf0.w[1] = kf0.w[2] = kf0.w[3] = 0u; \
        kf1.w[0] = kf1.w[1] = kf1.w[2] = kf1.w[3] = 0u; \
    } \
    const short8 vf = *(const short8*)&vbuf[((c) * 64 + lane) * 4]; \
    const float4v rc0 = *(const float4v*)&relw[(par) ? rb0x : ra0]; \
    const float4v rc1 = *(const float4v*)&relw[(par) ? rb1x : ra1]; \
    const float4v qk0 = __builtin_amdgcn_mfma_f32_16x16x32_bf16(kf0.v, qf.v, rc0, 0, 0, 0); \
    const float4v qk1 = __builtin_amdgcn_mfma_f32_16x16x32_bf16(kf1.v, qf.v, rc1, 0, 0, 0); \
    const float e0 = ex2(qk0[0]); \
    const float e1 = ex2(qk0[1]); \
    const float e2 = ex2(qk0[2]); \
    const float e3 = ex2(qk0[3]); \
    const float e4 = ex2(qk1[0]); \
    const float e5 = ex2(qk1[1]); \
    const float e6 = ex2(qk1[2]); \
    const float e7 = ex2(qk1[3]); \
    U8 pf; \
    pf.w[0] = pk2(e0, e1); \
    pf.w[1] = pk2(e2, e3); \
    pf.w[2] = pk2(e4, e5); \
    pf.w[3] = pk2(e6, e7); \
    accPV = __builtin_amdgcn_mfma_f32_16x16x32_bf16(pf.v, vf, accPV, 0, 0, 0); \
    accS  = __builtin_amdgcn_mfma_f32_16x16x32_bf16(pf.v, onef.v, accS, 0, 0, 0); \
    { U8 kr; kr.w[0] = ru0.x; kr.w[1] = ru0.y; kr.w[2] = ru0.z; kr.w[3] = ru0.w; \
      const float4v rx = __builtin_amdgcn_mfma_f32_16x16x32_bf16(kr.v, qf.v, zero4, 0, 0, 0); \
      relw[sw[par][0][0]] = rx[0]; relw[sw[par][0][1]] = rx[1]; \
      relw[sw[par][0][2]] = rx[2]; relw[sw[par][0][3]] = rx[3]; } \
    { U8 kr; kr.w[0] = ru1.x; kr.w[1] = ru1.y; kr.w[2] = ru1.z; kr.w[3] = ru1.w; \
      const float4v rx = __builtin_amdgcn_mfma_f32_16x16x32_bf16(kr.v, qf.v, zero4, 0, 0, 0); \
      relw[sw[par][1][0]] = rx[0]; relw[sw[par][1][1]] = rx[1]; \
      relw[sw[par][1][2]] = rx[2]; relw[sw[par][1][3]] = rx[3]; } \
    if ((c) < 8) { ru0 = rel_ld(2 * (c) + 23 - tt); ru1 = rel_ld(2 * (c) + 24 - tt); } \
}

        CHUNK(0, 0) CHUNK(1, 1) CHUNK(2, 0) CHUNK(3, 1) CHUNK(4, 0)
        CHUNK(5, 1) CHUNK(6, 0) CHUNK(7, 1) CHUNK(8, 0)
#undef CHUNK

        // ---- tail chunk 9: stile 18 only (s 288..303; s>=300 masked) ----
        {
            U8 kf0;
            if (quad < 2) {
                const uint4 u0 = *(const uint4*)&kbuf[(18 * 32 + quad * 16 + col) * 4];
                kf0.w[0] = u0.x; kf0.w[1] = u0.y; kf0.w[2] = u0.z; kf0.w[3] = u0.w;
            } else {
                kf0.w[0] = kf0.w[1] = kf0.w[2] = kf0.w[3] = 0u;
            }
            const float4v rc0 = *(const float4v*)&relw[rb0x];   // (288+4q)&63 = 4q^32
            const float4v qk0 = __builtin_amdgcn_mfma_f32_16x16x32_bf16(kf0.v, qf.v, rc0, 0, 0, 0);
            float e0 = ex2(qk0[0]);
            float e1 = ex2(qk0[1]);
            float e2 = ex2(qk0[2]);
            float e3 = ex2(qk0[3]);
            if (quad == 3) { e0 = e1 = e2 = e3 = 0.f; }
            U8 pf;
            pf.w[0] = pk2(e0, e1);
            pf.w[1] = pk2(e2, e3);
            pf.w[2] = 0u;
            pf.w[3] = 0u;
            const short8 vf = *(const short8*)&vbuf[(9 * 64 + lane) * 4];
            accPV = __builtin_amdgcn_mfma_f32_16x16x32_bf16(pf.v, vf, accPV, 0, 0, 0);
            accS  = __builtin_amdgcn_mfma_f32_16x16x32_bf16(pf.v, onef.v, accS, 0, 0, 0);
        }

        // ---- finalize: normalize, pair along d via shfl, store to
        // ah2[b][t][dp] (t-major). Even-col lanes write 4 u32 (t = t0+4q+r).
        // t >= 300 lands in the t<304 pad (never read by k_out). ----
        {
            float val[4];
            #pragma unroll
            for (int r = 0; r < 4; ++r) val[r] = accPV[r] * rcpf_(accS[r]);
            unsigned w[4];
            #pragma unroll
            for (int r = 0; r < 4; ++r) {
                const float p = __shfl_xor(val[r], 1);
                w[r] = pk2(val[r], p);
            }
            if ((col & 1) == 0) {
                const int dp = h * 8 + (col >> 1);
                unsigned* dst = ah_p + (size_t)(b * 304 + t0 + 4 * quad) * 32 + dp;
                #pragma unroll
                for (int r = 0; r < 4; ++r) dst[r * 32] = w[r];
            }
        }
    }
}

// ---------------------------------------------------------------------------
// k_out (MFMA): per (t-tile, n, t-quarter), 512 thr (waves = otile x t-half).
// ah staged from d-paired t-major ah2 via coalesced uint4 loads (128B runs
// per (b,t)) and uint4 LDS writes into the A-frag layout.
// ---------------------------------------------------------------------------
__global__ __launch_bounds__(512) void k_out(
        const float* __restrict__ x, const unsigned* __restrict__ W,
        float* __restrict__ out)
{
    const int tt = blockIdx.x, n = blockIdx.y, tq = blockIdx.z;
    if (tt == 18 && tq == 3) return;
    const int t0q = tt * 16 + tq * 4;
    const int tid = threadIdx.x;
    const unsigned* ah_p = W + WS_AH;
    const unsigned* awfrag = W + WS_AWF;
    const float* aoff = (const float*)(W + WS_AOFF);
    const float* scO  = (const float*)(W + WS_SCO);

    __shared__ unsigned fbuf[4 * 1024];    // 16 KB (ah A-frags)
    __shared__ float obuf[6400];           // 25.6 KB (x tile, then out tile)

    // stage x tile (64 o x 4 t x 25 v) via flat float4 (fully coalesced)
    for (int j = tid; j < 1600; j += 512) {
        const int o = j / 25, f4 = j - 25 * o;
        const float4 xv = *(const float4*)(x + (size_t)(n * 64 + o) * 7500 + t0q * 25 + f4 * 4);
        *(float4*)&obuf[o * 100 + f4 * 4] = xv;
    }
    // stage ah A-frags: 800 uint4 jobs = 25 v x 4 tl x 8 dp4.
    // Each uint4 = 4 consecutive dp words (pc = 4*dp4 + j2, j2 = 0..3) ->
    // 4 consecutive fbuf slots (ch = dp4>>2, qd = dp4&3, j2 runs 0..3).
    for (int i = tid; i < 800; i += 512) {
        const int dp4 = i & 7, g = i >> 3;
        const int tl = g & 3, v = g >> 2;
        const int b = n * 25 + v;
        const uint4 u = *(const uint4*)&ah_p[(size_t)(b * 304 + t0q + tl) * 32 + dp4 * 4];
        const int vt = v >> 4, cv = v & 15, ch = dp4 >> 2, qd = dp4 & 3;
        const int xi0 = (vt * 2 + ch) * 256 + (qd * 16 + (cv ^ qd)) * 4;
        *(uint4*)&fbuf[tl * 1024 + ((xi0 + 12 * tl) & 1023)] = u;
    }
    __syncthreads();

    const int wv = tid >> 6, lane = tid & 63, col = lane & 15, quad = lane >> 4;
    const int ow = wv & 3, th = wv >> 2;
    const int o = ow * 16 + col;
    const float4v zero4 = {0.f, 0.f, 0.f, 0.f};

    U8 awf0, awf1;
    { const uint4 u = *(const uint4*)&awfrag[(ow * 2 + 0) * 256 + lane * 4];
      awf0.w[0] = u.x; awf0.w[1] = u.y; awf0.w[2] = u.z; awf0.w[3] = u.w; }
    { const uint4 u = *(const uint4*)&awfrag[(ow * 2 + 1) * 256 + lane * 4];
      awf1.w[0] = u.x; awf1.w[1] = u.y; awf1.w[2] = u.z; awf1.w[3] = u.w; }
    const float aoff_l = aoff[o], sc_l = scO[o];

    for (int tl = 2 * th; tl < 2 * th + 2; ++tl) {
        #pragma unroll
        for (int vt = 0; vt < 2; ++vt) {
            U8 a0, a1;
            { const int xb = (vt * 2 + 0) * 256 + (quad * 16 + (col ^ quad)) * 4;
              const uint4 u = *(const uint4*)&fbuf[tl * 1024 + ((xb + 12 * tl) & 1023)];
              a0.w[0] = u.x; a0.w[1] = u.y; a0.w[2] = u.z; a0.w[3] = u.w; }
            { const int xb = (vt * 2 + 1) * 256 + (quad * 16 + (col ^ quad)) * 4;
              const uint4 u = *(const uint4*)&fbuf[tl * 1024 + ((xb + 12 * tl) & 1023)];
              a1.w[0] = u.x; a1.w[1] = u.y; a1.w[2] = u.z; a1.w[3] = u.w; }
            float4v acc = __builtin_amdgcn_mfma_f32_16x16x32_bf16(a0.v, awf0.v, zero4, 0, 0, 0);
            acc = __builtin_amdgcn_mfma_f32_16x16x32_bf16(a1.v, awf1.v, acc, 0, 0, 0);
            #pragma unroll
            for (int r = 0; r < 4; ++r) {
                const int v = vt * 16 + 4 * quad + r;
                if (v < 25) {
                    const int oi = o * 100 + tl * 25 + v;
                    obuf[oi] = fmaxf(fmaf(obuf[oi], sc_l, acc[r] + aoff_l), 0.f);
                }
            }
        }
    }
    __syncthreads();

    // flush out tile via flat float4 (fully coalesced)
    for (int j = tid; j < 1600; j += 512) {
        const int o2 = j / 25, f4 = j - 25 * o2;
        *(float4*)(out + (size_t)(n * 64 + o2) * 7500 + t0q * 25 + f4 * 4) =
            *(const float4*)&obuf[o2 * 100 + f4 * 4];
    }
}

// ---------------------------------------------------------------------------
extern "C" void kernel_launch(void* const* d_in, const int* in_sizes, int n_in,
                              void* d_out, int out_size, void* d_ws, size_t ws_size,
                              hipStream_t stream)
{
    const float* x       = (const float*)d_in[0];
    const float* dbn_g   = (const float*)d_in[1];
    const float* dbn_b   = (const float*)d_in[2];
    const float* dbn_m   = (const float*)d_in[3];
    const float* dbn_v   = (const float*)d_in[4];
    const float* qkv_w   = (const float*)d_in[5];
    const float* qkv_b   = (const float*)d_in[6];
    const float* key_rel = (const float*)d_in[7];
    const float* attn_w  = (const float*)d_in[8];
    const float* attn_b  = (const float*)d_in[9];
    const float* bn_g    = (const float*)d_in[10];
    const float* bn_b    = (const float*)d_in[11];
    const float* bn_m    = (const float*)d_in[12];
    const float* bn_v    = (const float*)d_in[13];
    float* out = (float*)d_out;
    unsigned* W = (unsigned*)d_ws;

    k_pre<<<26, 256, 0, stream>>>(dbn_g, dbn_b, dbn_m, dbn_v, qkv_w, qkv_b,
                                  key_rel, attn_w, attn_b, bn_g, bn_b, bn_m,
                                  bn_v, W);
    k_qkv<<<dim3(19, 16), 1024, 0, stream>>>(x, W);
    k_attn<<<1600, 256, 0, stream>>>(W);
    k_out<<<dim3(19, 16, 4), 512, 0, stream>>>(x, W, out);
}

// Round 11
// 197.342 us; speedup vs baseline: 1.2103x; 1.0215x over previous
//
#include <hip/hip_runtime.h>
#include <hip/hip_bf16.h>
#include <cstddef>

// Problem constants
#define NN 16
#define CC 64
#define TT 300
#define VV 25
#define NHH 4
#define DKHH 16
#define BB (NN * VV)          // 400
#define EPS 1e-5f
#define LOG2E 1.4426950408889634f

// Workspace layout (u32 units)
#define WS_QK    0            // u32[400][64][300]  q|k bf16, paired along o (q pre-scaled 0.25*log2e)
#define WS_V     7680000      // u32[400][64][152]  v bf16, paired along t (t>=300 zero-filled)
#define WS_AH    11571200     // u32[400][304][32]  attnh bf16, paired along d (dp), t-major
#define WS_REL   15462400     // u32[41][64][2] key_rel frags for 16x16x16 (slot = mtile+1, slot0 = zeros)
#define WS_AWF   15472896     // u32[4][2][64][4] attn_w B-frags (pre-scaled by bn scale)
#define WS_AOFF  15474944     // f32[64] fused attn_b+bn offset
#define WS_SCO   15475008     // f32[64] bn scale (for skip path)
#define WS_WFRAG 15475072     // u32[12][2][64][4] qkv_w B-frags (q pre-scaled 0.25*log2e)
#define WS_QB2   15481216     // f32[192] qkv_b (q pre-scaled)
#define WS_SCSH  15481408     // float2[1600] data_bn (sc, sh) per (c, v)

typedef __attribute__((ext_vector_type(8))) short short8;
typedef __attribute__((ext_vector_type(4))) short short4v;
typedef __attribute__((ext_vector_type(4))) float float4v;

union U8 { short8 v; unsigned int w[4]; };
union U4 { short4v v; unsigned int w[2]; };

// f32x2 -> packed bf16x2 (RNE). HW op if available, else manual.
__device__ __forceinline__ unsigned int pk2(float a, float b) {
#if __has_builtin(__builtin_amdgcn_cvt_pk_bf16_f32)
    typedef __attribute__((ext_vector_type(2))) __bf16 bf2;
    union { bf2 v; unsigned u; } c;
    c.v = __builtin_amdgcn_cvt_pk_bf16_f32(a, b);
    return c.u;
#else
    union { float f; unsigned u; } x, y;
    x.f = a; y.f = b;
    unsigned ua = x.u + 0x7FFFu + ((x.u >> 16) & 1u);
    unsigned ub = y.u + 0x7FFFu + ((y.u >> 16) & 1u);
    return (ua >> 16) | (ub & 0xFFFF0000u);
#endif
}

__device__ __forceinline__ float ex2(float x) {
#if __has_builtin(__builtin_amdgcn_exp2f)
    return __builtin_amdgcn_exp2f(x);
#else
    return exp2f(x);
#endif
}

__device__ __forceinline__ float rcpf_(float x) {
#if __has_builtin(__builtin_amdgcn_rcpf)
    return __builtin_amdgcn_rcpf(x);
#else
    return 1.f / x;
#endif
}

// K=16 MFMA (head dim is 16: no zero-padded K half). A/B = 2 VGPRs (4 bf16),
// C/D = 4 f32 with the SAME 16x16 C layout as the x32 variant.
__device__ __forceinline__ float4v mfma16(short4v a, short4v b, float4v c) {
#if __has_builtin(__builtin_amdgcn_mfma_f32_16x16x16_bf16)
    return __builtin_amdgcn_mfma_f32_16x16x16_bf16(a, b, c, 0, 0, 0);
#else
    return __builtin_amdgcn_mfma_f32_16x16x16bf16_1k(a, b, c, 0, 0, 0);
#endif
}

// ---------------------------------------------------------------------------
// k_pre: constant tables.
// ---------------------------------------------------------------------------
__global__ __launch_bounds__(256) void k_pre(
    const float* __restrict__ dbn_g, const float* __restrict__ dbn_b,
    const float* __restrict__ dbn_m, const float* __restrict__ dbn_v,
    const float* __restrict__ qkv_w, const float* __restrict__ qkv_b,
    const float* __restrict__ key_rel,
    const float* __restrict__ attn_w, const float* __restrict__ attn_b,
    const float* __restrict__ bn_g, const float* __restrict__ bn_b,
    const float* __restrict__ bn_m, const float* __restrict__ bn_v,
    unsigned* __restrict__ W)
{
    const int jid = blockIdx.x * 256 + threadIdx.x;
    if (jid < 2624) {                      // relfrag: 41 slots x 64 lanes, 16x16x16 A-frag
        const int k = jid >> 6, lane = jid & 63, col = lane & 15, quad = lane >> 4;
        const int mt = k - 1, m = mt * 16 + col;
        const bool ok = (mt >= 0) && (m < 2 * TT - 1);
        unsigned w[2];
        #pragma unroll
        for (int j = 0; j < 2; ++j) {
            const int c = quad * 4 + 2 * j;          // k = 4*quad + 2j, +1
            const float v0 = ok ? key_rel[m * 16 + c] : 0.f;
            const float v1 = ok ? key_rel[m * 16 + c + 1] : 0.f;
            w[j] = pk2(v0, v1);
        }
        *(uint2*)&W[WS_REL + k * 128 + lane * 2] = make_uint2(w[0], w[1]);
    } else if (jid < 3136) {               // awfrag: 4 otiles x 2 chalf x 64
        const int e = jid - 2624;
        const int ot = e >> 7, ch = (e >> 6) & 1, lane = e & 63;
        const int col = lane & 15, quad = lane >> 4;
        const int o = ot * 16 + col;
        const float sc = bn_g[o] * rsqrtf(bn_v[o] + EPS);
        unsigned w[4];
        #pragma unroll
        for (int j2 = 0; j2 < 4; ++j2) {
            const int c = ch * 32 + quad * 8 + 2 * j2;
            w[j2] = pk2(attn_w[o * 64 + c] * sc, attn_w[o * 64 + c + 1] * sc);
        }
        *(uint4*)&W[WS_AWF + (ot * 2 + ch) * 256 + lane * 4] = make_uint4(w[0], w[1], w[2], w[3]);
    } else if (jid < 3200) {               // aoff
        const int o = jid - 3136;
        const float sc = bn_g[o] * rsqrtf(bn_v[o] + EPS);
        ((float*)(W + WS_AOFF))[o] = attn_b[o] * sc + bn_b[o] - bn_m[o] * sc;
    } else if (jid < 3264) {               // scO
        const int o = jid - 3200;
        ((float*)(W + WS_SCO))[o] = bn_g[o] * rsqrtf(bn_v[o] + EPS);
    } else if (jid < 4800) {               // wfrag: 12 otiles x 2 chalf x 64
        const int e = jid - 3264;
        const int ot = e >> 7, ch = (e >> 6) & 1, lane = e & 63;
        const int col = lane & 15, quad = lane >> 4;
        const int o = ot * 16 + col;
        const float qs = (o < 64) ? 0.25f * LOG2E : 1.f;
        unsigned w[4];
        #pragma unroll
        for (int j2 = 0; j2 < 4; ++j2) {
            const int c = ch * 32 + quad * 8 + 2 * j2;
            w[j2] = pk2(qkv_w[o * 64 + c] * qs, qkv_w[o * 64 + c + 1] * qs);
        }
        *(uint4*)&W[WS_WFRAG + (ot * 2 + ch) * 256 + lane * 4] = make_uint4(w[0], w[1], w[2], w[3]);
    } else if (jid < 4992) {               // qb2
        const int o = jid - 4800;
        ((float*)(W + WS_QB2))[o] = qkv_b[o] * ((o < 64) ? 0.25f * LOG2E : 1.f);
    } else if (jid < 6592) {               // data_bn sc/sh per (c*25+v)
        const int e = jid - 4992;
        const float sc = dbn_g[e] * rsqrtf(dbn_v[e] + EPS);
        const float sh = dbn_b[e] - dbn_m[e] * sc;
        ((float2*)(W + WS_SCSH))[e] = make_float2(sc, sh);
    }
}

// ---------------------------------------------------------------------------
// k_qkv (MFMA): per (t-tile, n), 1024 thr (16 waves = 4 otg x 4 v-quarter).
// ---------------------------------------------------------------------------
__global__ __launch_bounds__(1024) void k_qkv(
        const float* __restrict__ x, unsigned* __restrict__ W)
{
    const int tt = blockIdx.x, n = blockIdx.y, t0 = tt * 16;
    const int tid = threadIdx.x;
    const unsigned* wfrag = W + WS_WFRAG;
    const float* qb2 = (const float*)(W + WS_QB2);
    unsigned* qk_p = W + WS_QK;
    unsigned* v_p  = W + WS_V;

    __shared__ unsigned afrag[25 * 516];   // 51.6 KB
    __shared__ float2 sls[1600];           // 12.8 KB data_bn (sc,sh) table

    for (int i = tid; i < 1600; i += 1024)
        sls[i] = ((const float2*)(W + WS_SCSH))[i];
    __syncthreads();

    // stage: 3200 jobs = 32 c-pairs x 100 float4 (contiguous flat = t*25+v)
    for (int i = tid; i < 3200; i += 1024) {
        const int f4 = i % 100, cp = i / 100;
        const int c0 = cp * 2;
        float4 xa = make_float4(0.f, 0.f, 0.f, 0.f);
        float4 xb = make_float4(0.f, 0.f, 0.f, 0.f);
        if (tt < 18 || f4 < 75) {          // tail tile: only 300 floats valid
            const float* p = x + (size_t)(n * 64 + c0) * 7500 + tt * 400 + f4 * 4;
            xa = *(const float4*)p;
            xb = *(const float4*)(p + 7500);
        }
        const int ch = cp >> 4, qd = (cp >> 2) & 3, j2 = cp & 3;
        const float ea[4] = {xa.x, xa.y, xa.z, xa.w};
        const float eb[4] = {xb.x, xb.y, xb.z, xb.w};
        #pragma unroll
        for (int e = 0; e < 4; ++e) {
            const int flat = f4 * 4 + e;
            const int tl = (flat * 5243) >> 17;     // flat / 25
            const int v  = flat - 25 * tl;
            const float2 s0 = sls[c0 * 25 + v];
            const float2 s1 = sls[c0 * 25 + 25 + v];
            const float a0 = fmaf(ea[e], s0.x, s0.y);
            const float a1 = fmaf(eb[e], s1.x, s1.y);
            afrag[v * 516 + (ch * 64 + qd * 16 + tl) * 4 + j2] = pk2(a0, a1);
        }
    }
    __syncthreads();

    const int wvv = tid >> 6, lane = tid & 63, col = lane & 15, quad = lane >> 4;
    const int otg = wvv >> 2, vq = wvv & 3;
    const int vlo = (vq == 0) ? 0 : (1 + 6 * vq);   // 0,7,13,19
    const int vhi = 7 + 6 * vq;                      // 7,13,19,25
    const float4v zero4 = {0.f, 0.f, 0.f, 0.f};
    const bool tvalid = (t0 + 4 * quad + 3 < TT);

    U8 bf[3][2]; float qb_l[3];
    #pragma unroll
    for (int i = 0; i < 3; ++i) {
        const int ot = 3 * otg + i;
        #pragma unroll
        for (int ch = 0; ch < 2; ++ch) {
            const uint4 u = *(const uint4*)&wfrag[(ot * 2 + ch) * 256 + lane * 4];
            bf[i][ch].w[0] = u.x; bf[i][ch].w[1] = u.y; bf[i][ch].w[2] = u.z; bf[i][ch].w[3] = u.w;
        }
        qb_l[i] = qb2[ot * 16 + col];
    }

    for (int v = vlo; v < vhi; ++v) {
        const int b = n * 25 + v;
        U8 a0, a1;
        { const uint4 u = *(const uint4*)&afrag[v * 516 + lane * 4];
          a0.w[0] = u.x; a0.w[1] = u.y; a0.w[2] = u.z; a0.w[3] = u.w; }
        { const uint4 u = *(const uint4*)&afrag[v * 516 + 256 + lane * 4];
          a1.w[0] = u.x; a1.w[1] = u.y; a1.w[2] = u.z; a1.w[3] = u.w; }
        #pragma unroll
        for (int i = 0; i < 3; ++i) {
            const int ot = 3 * otg + i;
            float4v acc = __builtin_amdgcn_mfma_f32_16x16x32_bf16(a0.v, bf[i][0].v, zero4, 0, 0, 0);
            acc = __builtin_amdgcn_mfma_f32_16x16x32_bf16(a1.v, bf[i][1].v, acc, 0, 0, 0);
            float val[4];
            #pragma unroll
            for (int r = 0; r < 4; ++r) val[r] = acc[r] + qb_l[i];
            if (ot < 8) {                  // q|k: pair neighbor o lanes
                unsigned pk[4];
                #pragma unroll
                for (int r = 0; r < 4; ++r) {
                    const float p = __shfl_xor(val[r], 1);
                    pk[r] = pk2(val[r], p);
                }
                if (((col & 1) == 0) && tvalid) {
                    const int op = ot * 8 + (col >> 1);
                    *(uint4*)&qk_p[(size_t)(b * 64 + op) * TT + t0 + 4 * quad] =
                        make_uint4(pk[0], pk[1], pk[2], pk[3]);
                }
            } else {                       // v: pair along t; zero-fill t>=300
                const int d = (ot - 8) * 16 + col;
                uint2 u;
                if (tvalid) { u.x = pk2(val[0], val[1]); u.y = pk2(val[2], val[3]); }
                else        { u.x = 0u; u.y = 0u; }
                *(uint2*)&v_p[(size_t)(b * 64 + d) * 152 + 8 * tt + 2 * quad] = u;
            }
        }
    }
}

// ---------------------------------------------------------------------------
// k_attn: ONE block per (b,h) (grid 1600, 4 waves), tiles strided by 4.
// QK and rel MFMAs use 16x16x16 (head dim IS 16 -- no zero-padded K half, no
// exec-mask branches, all-lane b64 kbuf reads). PV/rowsum stay 16x16x32
// (K = 32 real s values). Ring addresses precomputed (R10). Same ring
// memory pattern; C/D layout identical across both MFMA shapes.
// ---------------------------------------------------------------------------
__global__ __launch_bounds__(256, 4) void k_attn(unsigned* __restrict__ W)
{
    const int bh = blockIdx.x;             // 0..1599
    const int b = bh >> 2, h = bh & 3;
    const int tid  = threadIdx.x;
    const int wave = tid >> 6, lane = tid & 63;
    const int col  = lane & 15, quad = lane >> 4;

    const unsigned* qk_p = W + WS_QK;
    const unsigned* v_p  = W + WS_V;
    unsigned* ah_p = W + WS_AH;
    const unsigned* relfrag = W + WS_REL;

    __shared__ unsigned kbuf[19 * 64 * 2];   // 9.7 KB (16x16x16 A-frag layout)
    __shared__ unsigned vbuf[10 * 64 * 4];   // 10.2 KB (s-permuted)
    __shared__ float relbuf[4][16 * 68];     // per-wave s-ring (64 slots + pad)

    // K staging in the x16 A-frag layout: word j' of lane (quad,col) holds
    // k = 4*quad + 2j', +1  ->  qk_p o-pair index 2*quad + j'.
    for (int p = tid; p < 2432; p += 256) {
        const int c = p & 15, jp = (p >> 4) & 1, q2 = (p >> 5) & 3, st = p >> 7;
        kbuf[(st * 64 + q2 * 16 + c) * 2 + jp] =
            qk_p[(size_t)(b * 64 + 32 + h * 8 + 2 * q2 + jp) * TT + st * 16 + c];
    }
    // V staging with k<->s permutation: quad q of the PV A/B frag owns
    // s-pairs {2q, 2q+1, 8+2q, 8+2q+1} within each 32-s chunk.
    for (int p = tid; p < 640; p += 256) {
        const int tq = p % 40, d = p / 40;
        const int off = (tq * 4 <= 148) ? tq * 4 : 144;  // clamp (slots unused)
        const uint4 u = *(const uint4*)&v_p[(size_t)(b * 64 + h * 16 + d) * 152 + off];
        const int c = tq >> 2;
        const int l0 = (tq & 3) * 4;
        const unsigned uu[4] = {u.x, u.y, u.z, u.w};
        #pragma unroll
        for (int j = 0; j < 4; ++j) {
            const int local = l0 + j;
            const int q  = (local < 8) ? (local >> 1) : ((local - 8) >> 1);
            const int j2 = (local < 8) ? (local & 1) : (2 + (local & 1));
            vbuf[(c * 64 + q * 16 + d) * 4 + j2] = uu[j];
        }
    }
    __syncthreads();

    float* relw = &relbuf[wave][0];
    const float4v zero4 = {0.f, 0.f, 0.f, 0.f};
    U8 onef;
    onef.w[0] = onef.w[1] = onef.w[2] = onef.w[3] = 0x3F803F80u;

    // Loop-invariant ring offsets (R10): write slot base (357+4q+col) is
    // tt-invariant; chunk step +32 mod 64 = ^32 -> parity-alternating.
    int sw[2][2][4];
    #pragma unroll
    for (int j = 0; j < 4; ++j) {
        const int a  = (357 + 4 * quad + col + j) & 63;
        const int b2 = (373 + 4 * quad + col + j) & 63;
        sw[0][0][j] = col * 68 + a;
        sw[0][1][j] = col * 68 + b2;
        sw[1][0][j] = col * 68 + (a ^ 32);
        sw[1][1][j] = col * 68 + (b2 ^ 32);
    }
    const int ra0 = col * 68 + 4 * quad;
    const int ra1 = col * 68 + 4 * quad + 16;
    const int rb0x = col * 68 + (4 * quad ^ 32);
    const int rb1x = col * 68 + ((4 * quad + 16) ^ 32);

    for (int tt = wave; tt < 19; tt += 4) {
        const int t0 = tt * 16;

        // ---- Q B-frag (cols = t), x16 layout: word j' -> o-pair 2*quad+j' ----
        U4 qf;
        {
            int t = t0 + col; if (t > TT - 1) t = TT - 1;
            const size_t rb = (size_t)(b * 64 + h * 8 + 2 * quad) * TT + t;
            qf.w[0] = qk_p[rb];
            qf.w[1] = qk_p[rb + TT];
        }

        auto rel_ld = [&](int mt) -> uint2 {
            return *(const uint2*)&relfrag[(mt + 1) * 128 + lane * 2];
        };
        // generic (mod-form) rel_do for the prologue only (4 calls/tile)
        auto rel_do = [&](int mt, uint2 u) {
            U4 kr; kr.w[0] = u.x; kr.w[1] = u.y;
            const float4v rc = mfma16(kr.v, qf.v, zero4);
            const int wbase = mt * 16 + 4 * quad + t0 + col + 21;
            float* rw = &relw[col * 68];
            rw[wbase & 63]       = rc[0];
            rw[(wbase + 1) & 63] = rc[1];
            rw[(wbase + 2) & 63] = rc[2];
            rw[(wbase + 3) & 63] = rc[3];
        };

        #pragma unroll
        for (int i = 0; i < 4; ++i) rel_do(17 - tt + i, rel_ld(17 - tt + i));
        uint2 ru0 = rel_ld(21 - tt), ru1 = rel_ld(22 - tt);

        float4v accPV = zero4;
        float4v accS  = zero4;

#define CHUNK(c, par) { \
    U4 kf0, kf1; \
    { const uint2 u0 = *(const uint2*)&kbuf[((2 * (c)) * 64 + quad * 16 + col) * 2]; \
      const uint2 u1 = *(const uint2*)&kbuf[((2 * (c) + 1) * 64 + quad * 16 + col) * 2]; \
      kf0.w[0] = u0.x; kf0.w[1] = u0.y; \
      kf1.w[0] = u1.x; kf1.w[1] = u1.y; } \
    const short8 vf = *(const short8*)&vbuf[((c) * 64 + lane) * 4]; \
    const float4v rc0 = *(const float4v*)&relw[(par) ? rb0x : ra0]; \
    const float4v rc1 = *(const float4v*)&relw[(par) ? rb1x : ra1]; \
    const float4v qk0 = mfma16(kf0.v, qf.v, rc0); \
    const float4v qk1 = mfma16(kf1.v, qf.v, rc1); \
    const float e0 = ex2(qk0[0]); \
    const float e1 = ex2(qk0[1]); \
    const float e2 = ex2(qk0[2]); \
    const float e3 = ex2(qk0[3]); \
    const float e4 = ex2(qk1[0]); \
    const float e5 = ex2(qk1[1]); \
    const float e6 = ex2(qk1[2]); \
    const float e7 = ex2(qk1[3]); \
    U8 pf; \
    pf.w[0] = pk2(e0, e1); \
    pf.w[1] = pk2(e2, e3); \
    pf.w[2] = pk2(e4, e5); \
    pf.w[3] = pk2(e6, e7); \
    accPV = __builtin_amdgcn_mfma_f32_16x16x32_bf16(pf.v, vf, accPV, 0, 0, 0); \
    accS  = __builtin_amdgcn_mfma_f32_16x16x32_bf16(pf.v, onef.v, accS, 0, 0, 0); \
    { U4 kr; kr.w[0] = ru0.x; kr.w[1] = ru0.y; \
      const float4v rx = mfma16(kr.v, qf.v, zero4); \
      relw[sw[par][0][0]] = rx[0]; relw[sw[par][0][1]] = rx[1]; \
      relw[sw[par][0][2]] = rx[2]; relw[sw[par][0][3]] = rx[3]; } \
    { U4 kr; kr.w[0] = ru1.x; kr.w[1] = ru1.y; \
      const float4v rx = mfma16(kr.v, qf.v, zero4); \
      relw[sw[par][1][0]] = rx[0]; relw[sw[par][1][1]] = rx[1]; \
      relw[sw[par][1][2]] = rx[2]; relw[sw[par][1][3]] = rx[3]; } \
    if ((c) < 8) { ru0 = rel_ld(2 * (c) + 23 - tt); ru1 = rel_ld(2 * (c) + 24 - tt); } \
}

        CHUNK(0, 0) CHUNK(1, 1) CHUNK(2, 0) CHUNK(3, 1) CHUNK(4, 0)
        CHUNK(5, 1) CHUNK(6, 0) CHUNK(7, 1) CHUNK(8, 0)
#undef CHUNK

        // ---- tail chunk 9: stile 18 only (s 288..303; s>=300 masked) ----
        {
            U4 kf0;
            { const uint2 u0 = *(const uint2*)&kbuf[(18 * 64 + quad * 16 + col) * 2];
              kf0.w[0] = u0.x; kf0.w[1] = u0.y; }
            const float4v rc0 = *(const float4v*)&relw[rb0x];   // (288+4q)&63 = 4q^32
            const float4v qk0 = mfma16(kf0.v, qf.v, rc0);
            float e0 = ex2(qk0[0]);
            float e1 = ex2(qk0[1]);
            float e2 = ex2(qk0[2]);
            float e3 = ex2(qk0[3]);
            if (quad == 3) { e0 = e1 = e2 = e3 = 0.f; }
            U8 pf;
            pf.w[0] = pk2(e0, e1);
            pf.w[1] = pk2(e2, e3);
            pf.w[2] = 0u;
            pf.w[3] = 0u;
            const short8 vf = *(const short8*)&vbuf[(9 * 64 + lane) * 4];
            accPV = __builtin_amdgcn_mfma_f32_16x16x32_bf16(pf.v, vf, accPV, 0, 0, 0);
            accS  = __builtin_amdgcn_mfma_f32_16x16x32_bf16(pf.v, onef.v, accS, 0, 0, 0);
        }

        // ---- finalize: normalize, pair along d via shfl, store to
        // ah2[b][t][dp] (t-major). Even-col lanes write 4 u32 (t = t0+4q+r).
        // t >= 300 lands in the t<304 pad (never read by k_out). ----
        {
            float val[4];
            #pragma unroll
            for (int r = 0; r < 4; ++r) val[r] = accPV[r] * rcpf_(accS[r]);
            unsigned w[4];
            #pragma unroll
            for (int r = 0; r < 4; ++r) {
                const float p = __shfl_xor(val[r], 1);
                w[r] = pk2(val[r], p);
            }
            if ((col & 1) == 0) {
                const int dp = h * 8 + (col >> 1);
                unsigned* dst = ah_p + (size_t)(b * 304 + t0 + 4 * quad) * 32 + dp;
                #pragma unroll
                for (int r = 0; r < 4; ++r) dst[r * 32] = w[r];
            }
        }
    }
}

// ---------------------------------------------------------------------------
// k_out (MFMA): per (t-tile, n, t-quarter), 512 thr (waves = otile x t-half).
// ah staged from d-paired t-major ah2 via coalesced uint4 loads (128B runs
// per (b,t)) and uint4 LDS writes into the A-frag layout.
// ---------------------------------------------------------------------------
__global__ __launch_bounds__(512) void k_out(
        const float* __restrict__ x, const unsigned* __restrict__ W,
        float* __restrict__ out)
{
    const int tt = blockIdx.x, n = blockIdx.y, tq = blockIdx.z;
    if (tt == 18 && tq == 3) return;
    const int t0q = tt * 16 + tq * 4;
    const int tid = threadIdx.x;
    const unsigned* ah_p = W + WS_AH;
    const unsigned* awfrag = W + WS_AWF;
    const float* aoff = (const float*)(W + WS_AOFF);
    const float* scO  = (const float*)(W + WS_SCO);

    __shared__ unsigned fbuf[4 * 1024];    // 16 KB (ah A-frags)
    __shared__ float obuf[6400];           // 25.6 KB (x tile, then out tile)

    // stage x tile (64 o x 4 t x 25 v) via flat float4 (fully coalesced)
    for (int j = tid; j < 1600; j += 512) {
        const int o = j / 25, f4 = j - 25 * o;
        const float4 xv = *(const float4*)(x + (size_t)(n * 64 + o) * 7500 + t0q * 25 + f4 * 4);
        *(float4*)&obuf[o * 100 + f4 * 4] = xv;
    }
    // stage ah A-frags: 800 uint4 jobs = 25 v x 4 tl x 8 dp4.
    for (int i = tid; i < 800; i += 512) {
        const int dp4 = i & 7, g = i >> 3;
        const int tl = g & 3, v = g >> 2;
        const int b = n * 25 + v;
        const uint4 u = *(const uint4*)&ah_p[(size_t)(b * 304 + t0q + tl) * 32 + dp4 * 4];
        const int vt = v >> 4, cv = v & 15, ch = dp4 >> 2, qd = dp4 & 3;
        const int xi0 = (vt * 2 + ch) * 256 + (qd * 16 + (cv ^ qd)) * 4;
        *(uint4*)&fbuf[tl * 1024 + ((xi0 + 12 * tl) & 1023)] = u;
    }
    __syncthreads();

    const int wv = tid >> 6, lane = tid & 63, col = lane & 15, quad = lane >> 4;
    const int ow = wv & 3, th = wv >> 2;
    const int o = ow * 16 + col;
    const float4v zero4 = {0.f, 0.f, 0.f, 0.f};

    U8 awf0, awf1;
    { const uint4 u = *(const uint4*)&awfrag[(ow * 2 + 0) * 256 + lane * 4];
      awf0.w[0] = u.x; awf0.w[1] = u.y; awf0.w[2] = u.z; awf0.w[3] = u.w; }
    { const uint4 u = *(const uint4*)&awfrag[(ow * 2 + 1) * 256 + lane * 4];
      awf1.w[0] = u.x; awf1.w[1] = u.y; awf1.w[2] = u.z; awf1.w[3] = u.w; }
    const float aoff_l = aoff[o], sc_l = scO[o];

    for (int tl = 2 * th; tl < 2 * th + 2; ++tl) {
        #pragma unroll
        for (int vt = 0; vt < 2; ++vt) {
            U8 a0, a1;
            { const int xb = (vt * 2 + 0) * 256 + (quad * 16 + (col ^ quad)) * 4;
              const uint4 u = *(const uint4*)&fbuf[tl * 1024 + ((xb + 12 * tl) & 1023)];
              a0.w[0] = u.x; a0.w[1] = u.y; a0.w[2] = u.z; a0.w[3] = u.w; }
            { const int xb = (vt * 2 + 1) * 256 + (quad * 16 + (col ^ quad)) * 4;
              const uint4 u = *(const uint4*)&fbuf[tl * 1024 + ((xb + 12 * tl) & 1023)];
              a1.w[0] = u.x; a1.w[1] = u.y; a1.w[2] = u.z; a1.w[3] = u.w; }
            float4v acc = __builtin_amdgcn_mfma_f32_16x16x32_bf16(a0.v, awf0.v, zero4, 0, 0, 0);
            acc = __builtin_amdgcn_mfma_f32_16x16x32_bf16(a1.v, awf1.v, acc, 0, 0, 0);
            #pragma unroll
            for (int r = 0; r < 4; ++r) {
                const int v = vt * 16 + 4 * quad + r;
                if (v < 25) {
                    const int oi = o * 100 + tl * 25 + v;
                    obuf[oi] = fmaxf(fmaf(obuf[oi], sc_l, acc[r] + aoff_l), 0.f);
                }
            }
        }
    }
    __syncthreads();

    // flush out tile via flat float4 (fully coalesced)
    for (int j = tid; j < 1600; j += 512) {
        const int o2 = j / 25, f4 = j - 25 * o2;
        *(float4*)(out + (size_t)(n * 64 + o2) * 7500 + t0q * 25 + f4 * 4) =
            *(const float4*)&obuf[o2 * 100 + f4 * 4];
    }
}

// ---------------------------------------------------------------------------
extern "C" void kernel_launch(void* const* d_in, const int* in_sizes, int n_in,
                              void* d_out, int out_size, void* d_ws, size_t ws_size,
                              hipStream_t stream)
{
    const float* x       = (const float*)d_in[0];
    const float* dbn_g   = (const float*)d_in[1];
    const float* dbn_b   = (const float*)d_in[2];
    const float* dbn_m   = (const float*)d_in[3];
    const float* dbn_v   = (const float*)d_in[4];
    const float* qkv_w   = (const float*)d_in[5];
    const float* qkv_b   = (const float*)d_in[6];
    const float* key_rel = (const float*)d_in[7];
    const float* attn_w  = (const float*)d_in[8];
    const float* attn_b  = (const float*)d_in[9];
    const float* bn_g    = (const float*)d_in[10];
    const float* bn_b    = (const float*)d_in[11];
    const float* bn_m    = (const float*)d_in[12];
    const float* bn_v    = (const float*)d_in[13];
    float* out = (float*)d_out;
    unsigned* W = (unsigned*)d_ws;

    k_pre<<<26, 256, 0, stream>>>(dbn_g, dbn_b, dbn_m, dbn_v, qkv_w, qkv_b,
                                  key_rel, attn_w, attn_b, bn_g, bn_b, bn_m,
                                  bn_v, W);
    k_qkv<<<dim3(19, 16), 1024, 0, stream>>>(x, W);
    k_attn<<<1600, 256, 0, stream>>>(W);
    k_out<<<dim3(19, 16, 4), 512, 0, stream>>>(x, W, out);
}